// Round 1
// 2281.527 us; speedup vs baseline: 1.3965x; 1.3965x over previous
//
#include <hip/hip_runtime.h>
#include <math.h>

#define B_ 256
#define T_ 64
#define DOBS 512
#define D_ 128
#define N_ 16
#define H_ 256

typedef unsigned short u16;
typedef short bf16x8 __attribute__((ext_vector_type(8)));
typedef float f32x4 __attribute__((ext_vector_type(4)));

union FragU { bf16x8 v; uint4 u; };

#define MFMA(ACC, A, Bv) (ACC) = __builtin_amdgcn_mfma_f32_16x16x32_bf16((A), (Bv), (ACC), 0, 0, 0)
#define MFMA2(ACC, AH, AL, Bv) do { MFMA(ACC, AH, Bv); MFMA(ACC, AL, Bv); } while (0)

// ws layout (u16 elements), all matrices transposed to [n][k] bf16:
#define OFF_EW1T   0        // 256x512
#define OFF_EW2T   131072   // 128x256
#define OFF_SKIPT  163840   // 128x512
#define OFF_WKVT   229376   // 256x128 (rows 0-127 Wk, 128-255 Wv)
#define OFF_WQT    262144   // 128x128
#define OFF_WIHT   278528   // 384x128
#define OFF_WHHT   327680   // 384x128
#define OFF_MW1T   376832   // 128x128
#define OFF_MW2T   393216   // 128x128
#define OFF_WTT    409600   // 128x128

__device__ __forceinline__ unsigned rne16(float f) {
    unsigned u = __float_as_uint(f);
    return (u + 0x7FFFu + ((u >> 16) & 1u)) >> 16;
}
__device__ __forceinline__ float fromhi(unsigned h) { return __uint_as_float(h << 16); }
__device__ __forceinline__ u16 f2b(float f) { return (u16)rne16(f); }
__device__ __forceinline__ float sigmoidf_(float x) { return 1.0f / (1.0f + expf(-x)); }

__device__ __forceinline__ void mk_pack(const float* x, FragU& fh, FragU& fl) {
    unsigned h[8], l[8];
#pragma unroll
    for (int j = 0; j < 8; ++j) {
        h[j] = rne16(x[j]);
        l[j] = rne16(x[j] - fromhi(h[j]));
    }
    fh.u = make_uint4(h[0] | (h[1] << 16), h[2] | (h[3] << 16), h[4] | (h[5] << 16), h[6] | (h[7] << 16));
    fl.u = make_uint4(l[0] | (l[1] << 16), l[2] | (l[3] << 16), l[4] | (l[5] << 16), l[6] | (l[7] << 16));
}

__device__ __forceinline__ void mk_raw(const float* p, FragU& fh, FragU& fl) {
    float4 a = *(const float4*)p, b = *(const float4*)(p + 4);
    float x[8] = {a.x, a.y, a.z, a.w, b.x, b.y, b.z, b.w};
    mk_pack(x, fh, fl);
}

__device__ __forceinline__ void mk_aff(const float* p, float mu, float rs,
                                       const float* gp, const float* bp,
                                       FragU& fh, FragU& fl) {
    float4 a = *(const float4*)p, b = *(const float4*)(p + 4);
    float4 g0 = *(const float4*)gp, g1 = *(const float4*)(gp + 4);
    float4 b0 = *(const float4*)bp, b1 = *(const float4*)(bp + 4);
    float x[8];
    x[0] = (a.x - mu) * rs * g0.x + b0.x;  x[1] = (a.y - mu) * rs * g0.y + b0.y;
    x[2] = (a.z - mu) * rs * g0.z + b0.z;  x[3] = (a.w - mu) * rs * g0.w + b0.w;
    x[4] = (b.x - mu) * rs * g1.x + b1.x;  x[5] = (b.y - mu) * rs * g1.y + b1.y;
    x[6] = (b.z - mu) * rs * g1.z + b1.z;  x[7] = (b.w - mu) * rs * g1.w + b1.w;
    mk_pack(x, fh, fl);
}

__device__ __forceinline__ void mk_scaled(const float* p, float sc, FragU& fh, FragU& fl) {
    float4 a = *(const float4*)p, b = *(const float4*)(p + 4);
    float x[8] = {sc * a.x, sc * a.y, sc * a.z, sc * a.w, sc * b.x, sc * b.y, sc * b.z, sc * b.w};
    mk_pack(x, fh, fl);
}

// select acc[q] without runtime indexing (rule #20: dynamic index -> scratch)
__device__ __forceinline__ f32x4 sel4(const f32x4* a, int q) {
    f32x4 r = a[0];
    if (q == 1) r = a[1];
    if (q == 2) r = a[2];
    if (q == 3) r = a[3];
    return r;
}

// ---------------- weight prepass: fp32 [k][n] -> bf16 [n][k] ----------------
__global__ __launch_bounds__(256) void prep_kernel(
    const float* __restrict__ eW1, const float* __restrict__ eW2, const float* __restrict__ skipW,
    const float* __restrict__ Wk, const float* __restrict__ Wv, const float* __restrict__ Wq,
    const float* __restrict__ Wih, const float* __restrict__ Whh,
    const float* __restrict__ mW1, const float* __restrict__ mW2, const float* __restrict__ Wt,
    u16* __restrict__ ws)
{
    int id = blockIdx.y;
    const float* src; int dstoff, logk, N;
    switch (id) {
        case 0:  src = eW1;   dstoff = OFF_EW1T;  logk = 9; N = 256; break;
        case 1:  src = eW2;   dstoff = OFF_EW2T;  logk = 8; N = 128; break;
        case 2:  src = skipW; dstoff = OFF_SKIPT; logk = 9; N = 128; break;
        case 3:  src = Wk;    dstoff = OFF_WKVT;  logk = 7; N = 128; break;
        case 4:  src = Wv;    dstoff = OFF_WKVT + 16384; logk = 7; N = 128; break;
        case 5:  src = Wq;    dstoff = OFF_WQT;   logk = 7; N = 128; break;
        case 6:  src = Wih;   dstoff = OFF_WIHT;  logk = 7; N = 384; break;
        case 7:  src = Whh;   dstoff = OFF_WHHT;  logk = 7; N = 384; break;
        case 8:  src = mW1;   dstoff = OFF_MW1T;  logk = 7; N = 128; break;
        case 9:  src = mW2;   dstoff = OFF_MW2T;  logk = 7; N = 128; break;
        default: src = Wt;    dstoff = OFF_WTT;   logk = 7; N = 128; break;
    }
    int idx = blockIdx.x * 256 + threadIdx.x;
    int K = 1 << logk;
    if (idx < K * N) {
        int n = idx >> logk, k = idx & (K - 1);
        ws[dstoff + idx] = f2b(src[k * N + n]);
    }
}

// ---------------- main fused kernel: 4 (b,t) rows per block ----------------
__global__ __launch_bounds__(256) void sa2_kernel(
    const float* __restrict__ obs,
    const float* __restrict__ eb1, const float* __restrict__ eb2,
    const float* __restrict__ slot_mu,
    const float* __restrict__ bih, const float* __restrict__ bhh,
    const float* __restrict__ mb1, const float* __restrict__ mb2,
    const float* __restrict__ g_in, const float* __restrict__ be_in,
    const float* __restrict__ g_sl, const float* __restrict__ be_sl,
    const float* __restrict__ g_ml, const float* __restrict__ be_ml,
    const u16* __restrict__ ws, float* __restrict__ out)
{
    __shared__ __align__(16) float slots_s[64 * 132];      // 33792 B
    __shared__ __align__(16) float scratch[4352];          // enc: obs(4x516)+h(4x260)+z(4x132); iter: hid u16 4x16x136
    __shared__ __align__(16) float k_s[4 * 132];
    __shared__ __align__(16) float v_s[4 * 132];
    __shared__ __align__(16) float par_s[6 * 128];         // gin, bin, gsl, bsl, gml, bml
    __shared__ __align__(16) float bias_s[512];            // b_rz[256], bin_[128], bhn_[128]
    __shared__ float rs_s[64];
    __shared__ float logit_s[64];
    __shared__ float zmu_s[4], zrs_s[4];

    float* obs_s = scratch;            // 4 x 516
    float* h_s   = scratch + 2064;     // 4 x 260
    float* z_s   = scratch + 3104;     // 4 x 132
    u16*   hid_s = (u16*)scratch;      // 4 groups x 16 x 136 (iter phase)

    const int tid = threadIdx.x;
    const int wave = tid >> 6, lane = tid & 63;
    const int l15 = lane & 15, quad = lane >> 4;
    const int r0 = blockIdx.x * 4;

    // ---- stage params / biases / obs ----
    if (tid < 128) {
        par_s[tid]       = g_in[tid];  par_s[128 + tid] = be_in[tid];
        par_s[256 + tid] = g_sl[tid];  par_s[384 + tid] = be_sl[tid];
        par_s[512 + tid] = g_ml[tid];  par_s[640 + tid] = be_ml[tid];
        bias_s[256 + tid] = bih[256 + tid];
        bias_s[384 + tid] = bhh[256 + tid];
    }
    if (tid < 256) bias_s[tid] = bih[tid] + bhh[tid];
    for (int i4 = tid; i4 < 512; i4 += 256) {
        int g2 = i4 >> 7, c4 = i4 & 127;
        *((float4*)(obs_s + g2 * 516) + c4) = *((const float4*)(obs + (size_t)(r0 + g2) * 512) + c4);
    }
    __syncthreads();

    // ---- encoder layer 1: h = gelu(obs@W1 + b1); M-tile has rows 0-3 valid ----
    {
        f32x4 acc[4] = {{0}, {0}, {0}, {0}};
        const float* abase = obs_s + (l15 & 3) * 516;
#pragma unroll 1
        for (int ks = 0; ks < 16; ++ks) {
            FragU ah, al;
            mk_raw(abase + ks * 32 + quad * 8, ah, al);
#pragma unroll
            for (int tt = 0; tt < 4; ++tt) {
                int row = (wave * 4 + tt) * 16 + l15;
                FragU b; b.u = *(const uint4*)(ws + OFF_EW1T + row * 512 + ks * 32 + quad * 8);
                MFMA2(acc[tt], ah.v, al.v, b.v);
            }
        }
        // C-rows are quad-replicated (A rows are l15&3): quad q holds the same
        // group values as quad 0 -> parallelize gelu across quads (tt = quad).
        {
            f32x4 av = sel4(acc, quad);
            int col = (wave * 4 + quad) * 16 + l15;
            float bb = eb1[col];
#pragma unroll
            for (int reg = 0; reg < 4; ++reg) {
                float x = av[reg] + bb;
                h_s[reg * 260 + col] = 0.5f * x * (1.0f + erff(x * 0.7071067811865475f));
            }
        }
    }
    __syncthreads();

    // ---- z = tanh(h@W2 + b2 + obs@skip) ----
    {
        f32x4 acc[2] = {{0}, {0}};
        const float* hbase = h_s + (l15 & 3) * 260;
#pragma unroll 1
        for (int ks = 0; ks < 8; ++ks) {
            FragU ah, al;
            mk_raw(hbase + ks * 32 + quad * 8, ah, al);
#pragma unroll
            for (int tt = 0; tt < 2; ++tt) {
                int row = (wave * 2 + tt) * 16 + l15;
                FragU b; b.u = *(const uint4*)(ws + OFF_EW2T + row * 256 + ks * 32 + quad * 8);
                MFMA2(acc[tt], ah.v, al.v, b.v);
            }
        }
        const float* obase = obs_s + (l15 & 3) * 516;
#pragma unroll 1
        for (int ks = 0; ks < 16; ++ks) {
            FragU ah, al;
            mk_raw(obase + ks * 32 + quad * 8, ah, al);
#pragma unroll
            for (int tt = 0; tt < 2; ++tt) {
                int row = (wave * 2 + tt) * 16 + l15;
                FragU b; b.u = *(const uint4*)(ws + OFF_SKIPT + row * 512 + ks * 32 + quad * 8);
                MFMA2(acc[tt], ah.v, al.v, b.v);
            }
        }
        if (quad < 2) {
            f32x4 av = (quad == 0) ? acc[0] : acc[1];
            int col = (wave * 2 + quad) * 16 + l15;
            float bb = eb2[col];
#pragma unroll
            for (int reg = 0; reg < 4; ++reg)
                z_s[reg * 132 + col] = tanhf(av[reg] + bb);
        }
    }
    __syncthreads();

    // ---- LN(z) stats: wave w computes row w stats in parallel ----
    {
        const float* row = z_s + wave * 132;
        float x0 = row[lane], x1 = row[64 + lane];
        float s = x0 + x1;
        s += __shfl_xor(s, 1);  s += __shfl_xor(s, 2);  s += __shfl_xor(s, 4);
        s += __shfl_xor(s, 8);  s += __shfl_xor(s, 16); s += __shfl_xor(s, 32);
        float mu = s * (1.0f / 128.0f);
        float d0 = x0 - mu, d1 = x1 - mu;
        float v = fmaf(d0, d0, d1 * d1);
        v += __shfl_xor(v, 1);  v += __shfl_xor(v, 2);  v += __shfl_xor(v, 4);
        v += __shfl_xor(v, 8);  v += __shfl_xor(v, 16); v += __shfl_xor(v, 32);
        if (lane == 0) { zmu_s[wave] = mu; zrs_s[wave] = rsqrtf(v * (1.0f / 128.0f) + 1e-5f); }
    }
    __syncthreads();

    // ---- k,v = LN(z) @ [Wk|Wv] ----
    {
        f32x4 acc[4] = {{0}, {0}, {0}, {0}};
        const float* zbase = z_s + (l15 & 3) * 132;
        float zmu = zmu_s[l15 & 3], zrs = zrs_s[l15 & 3];
#pragma unroll 1
        for (int ks = 0; ks < 4; ++ks) {
            FragU ah, al;
            mk_aff(zbase + ks * 32 + quad * 8, zmu, zrs,
                   par_s + ks * 32 + quad * 8, par_s + 128 + ks * 32 + quad * 8, ah, al);
#pragma unroll
            for (int tt = 0; tt < 4; ++tt) {
                int row = (wave * 4 + tt) * 16 + l15;
                FragU b; b.u = *(const uint4*)(ws + OFF_WKVT + row * 128 + ks * 32 + quad * 8);
                MFMA2(acc[tt], ah.v, al.v, b.v);
            }
        }
        {
            f32x4 av = sel4(acc, quad);
            int col = (wave * 4 + quad) * 16 + l15;
#pragma unroll
            for (int reg = 0; reg < 4; ++reg) {
                if (col < 128) k_s[reg * 132 + col] = av[reg];
                else           v_s[reg * 132 + col - 128] = av[reg];
            }
        }
    }
    __syncthreads();   // LAST block-wide barrier: after this each wave touches only its group

    // ---- slot loop: wave w owns group g=w; fully wave-independent from here ----
    const int g = wave;
    const int srow0 = g * 16;
    for (int i4 = lane; i4 < 512; i4 += 64) {
        int row = i4 >> 5, c4 = i4 & 31;
        *((float4*)(slots_s + (srow0 + row) * 132) + c4) = *((const float4*)slot_mu + i4);
    }

    for (int iter = 0; iter < 3; ++iter) {
        // LN stats of own row (l15); strided-4 reads (2-way free), 4 partial sums
        float myMu, myRs;
        {
            const float* rowp = slots_s + (srow0 + l15) * 132;
            float s0 = 0, s1 = 0, s2 = 0, s3 = 0;
#pragma unroll
            for (int j = 0; j < 8; ++j) {
                s0 += rowp[quad + 16 * j];
                s1 += rowp[quad + 16 * j + 4];
                s2 += rowp[quad + 16 * j + 8];
                s3 += rowp[quad + 16 * j + 12];
            }
            float s = (s0 + s1) + (s2 + s3);
            s += __shfl_xor(s, 16); s += __shfl_xor(s, 32);
            myMu = s * (1.0f / 128.0f);
            float v0 = 0, v1 = 0, v2 = 0, v3 = 0;
#pragma unroll
            for (int j = 0; j < 8; ++j) {
                float d0 = rowp[quad + 16 * j] - myMu;      v0 = fmaf(d0, d0, v0);
                float d1 = rowp[quad + 16 * j + 4] - myMu;  v1 = fmaf(d1, d1, v1);
                float d2 = rowp[quad + 16 * j + 8] - myMu;  v2 = fmaf(d2, d2, v2);
                float d3 = rowp[quad + 16 * j + 12] - myMu; v3 = fmaf(d3, d3, v3);
            }
            float v = (v0 + v1) + (v2 + v3);
            v += __shfl_xor(v, 16); v += __shfl_xor(v, 32);
            myRs = rsqrtf(v * (1.0f / 128.0f) + 1e-5f);
        }

        // ---- q = LN(slots)@Wq fused with logits ----
        {
            FragU ah[4], al[4];
#pragma unroll
            for (int ks = 0; ks < 4; ++ks)
                mk_aff(slots_s + (srow0 + l15) * 132 + ks * 32 + quad * 8, myMu, myRs,
                       par_s + 256 + ks * 32 + quad * 8, par_s + 384 + ks * 32 + quad * 8,
                       ah[ks], al[ks]);
            float lp[4] = {0, 0, 0, 0};
#pragma unroll 1
            for (int t = 0; t < 8; ++t) {
                f32x4 a = {0};
#pragma unroll
                for (int ks = 0; ks < 4; ++ks) {
                    FragU b; b.u = *(const uint4*)(ws + OFF_WQT + (t * 16 + l15) * 128 + ks * 32 + quad * 8);
                    MFMA2(a, ah[ks].v, al[ks].v, b.v);
                }
                float kc = k_s[g * 132 + t * 16 + l15];
#pragma unroll
                for (int reg = 0; reg < 4; ++reg) lp[reg] = fmaf(a[reg], kc, lp[reg]);
            }
#pragma unroll
            for (int reg = 0; reg < 4; ++reg) {
                lp[reg] += __shfl_xor(lp[reg], 1);
                lp[reg] += __shfl_xor(lp[reg], 2);
                lp[reg] += __shfl_xor(lp[reg], 4);
                lp[reg] += __shfl_xor(lp[reg], 8);
            }
            if (l15 == 0) {
#pragma unroll
                for (int reg = 0; reg < 4; ++reg)
                    logit_s[srow0 + quad * 4 + reg] = lp[reg] * 0.08838834764831845f;
            }
        }

        // softmax over 16 slots: shuffle reduce within 16-lane group (1 exp/lane)
        float attn_me;
        {
            float x = logit_s[srow0 + l15];
            float mx = fmaxf(x, __shfl_xor(x, 1));
            mx = fmaxf(mx, __shfl_xor(mx, 2));
            mx = fmaxf(mx, __shfl_xor(mx, 4));
            mx = fmaxf(mx, __shfl_xor(mx, 8));
            float e = expf(x - mx);
            float den = e;
            den += __shfl_xor(den, 1);
            den += __shfl_xor(den, 2);
            den += __shfl_xor(den, 4);
            den += __shfl_xor(den, 8);
            attn_me = e / den;
        }

        // ---- GRU via MFMA ----
        {
            FragU auh[4], aul[4], ash[4], asl[4];
#pragma unroll
            for (int ks = 0; ks < 4; ++ks) {
                mk_scaled(v_s + g * 132 + ks * 32 + quad * 8, attn_me, auh[ks], aul[ks]);
                mk_raw(slots_s + (srow0 + l15) * 132 + ks * 32 + quad * 8, ash[ks], asl[ks]);
            }
#pragma unroll 1
            for (int cg = 0; cg < 8; ++cg) {
                f32x4 ar = {0}, az = {0}, ani = {0}, anh = {0};
                const int rowb = cg * 16 + l15;
#pragma unroll
                for (int ks = 0; ks < 4; ++ks) {
                    const int koff = ks * 32 + quad * 8;
                    FragU b;
                    b.u = *(const uint4*)(ws + OFF_WIHT + rowb * 128 + koff);
                    MFMA2(ar, auh[ks].v, aul[ks].v, b.v);
                    b.u = *(const uint4*)(ws + OFF_WHHT + rowb * 128 + koff);
                    MFMA2(ar, ash[ks].v, asl[ks].v, b.v);
                    b.u = *(const uint4*)(ws + OFF_WIHT + (128 + rowb) * 128 + koff);
                    MFMA2(az, auh[ks].v, aul[ks].v, b.v);
                    b.u = *(const uint4*)(ws + OFF_WHHT + (128 + rowb) * 128 + koff);
                    MFMA2(az, ash[ks].v, asl[ks].v, b.v);
                    b.u = *(const uint4*)(ws + OFF_WIHT + (256 + rowb) * 128 + koff);
                    MFMA2(ani, auh[ks].v, aul[ks].v, b.v);
                    b.u = *(const uint4*)(ws + OFF_WHHT + (256 + rowb) * 128 + koff);
                    MFMA2(anh, ash[ks].v, asl[ks].v, b.v);
                }
                const int cc = cg * 16 + l15;
#pragma unroll
                for (int reg = 0; reg < 4; ++reg) {
                    int row = srow0 + quad * 4 + reg;
                    float rg = sigmoidf_(ar[reg] + bias_s[cc]);
                    float zg = sigmoidf_(az[reg] + bias_s[128 + cc]);
                    float ng = tanhf(ani[reg] + bias_s[256 + cc] + rg * (anh[reg] + bias_s[384 + cc]));
                    float hp = slots_s[row * 132 + cc];
                    slots_s[row * 132 + cc] = (1.0f - zg) * ng + zg * hp;
                }
            }
        }

        // ---- MLP: slots += relu(LN(slots)@W1+b1)@W2+b2 ----
        {
            const float* rowp = slots_s + (srow0 + l15) * 132;
            float s0 = 0, s1 = 0, s2 = 0, s3 = 0;
#pragma unroll
            for (int j = 0; j < 8; ++j) {
                s0 += rowp[quad + 16 * j];
                s1 += rowp[quad + 16 * j + 4];
                s2 += rowp[quad + 16 * j + 8];
                s3 += rowp[quad + 16 * j + 12];
            }
            float s = (s0 + s1) + (s2 + s3);
            s += __shfl_xor(s, 16); s += __shfl_xor(s, 32);
            float mu2 = s * (1.0f / 128.0f);
            float v0 = 0, v1 = 0, v2 = 0, v3 = 0;
#pragma unroll
            for (int j = 0; j < 8; ++j) {
                float d0 = rowp[quad + 16 * j] - mu2;      v0 = fmaf(d0, d0, v0);
                float d1 = rowp[quad + 16 * j + 4] - mu2;  v1 = fmaf(d1, d1, v1);
                float d2 = rowp[quad + 16 * j + 8] - mu2;  v2 = fmaf(d2, d2, v2);
                float d3 = rowp[quad + 16 * j + 12] - mu2; v3 = fmaf(d3, d3, v3);
            }
            float v = (v0 + v1) + (v2 + v3);
            v += __shfl_xor(v, 16); v += __shfl_xor(v, 32);
            float rs2 = rsqrtf(v * (1.0f / 128.0f) + 1e-5f);

            FragU ah[4], al[4];
#pragma unroll
            for (int ks = 0; ks < 4; ++ks)
                mk_aff(rowp + ks * 32 + quad * 8, mu2, rs2,
                       par_s + 512 + ks * 32 + quad * 8, par_s + 640 + ks * 32 + quad * 8,
                       ah[ks], al[ks]);
#pragma unroll 1
            for (int t = 0; t < 8; ++t) {
                f32x4 a = {0};
#pragma unroll
                for (int ks = 0; ks < 4; ++ks) {
                    FragU b; b.u = *(const uint4*)(ws + OFF_MW1T + (t * 16 + l15) * 128 + ks * 32 + quad * 8);
                    MFMA2(a, ah[ks].v, al[ks].v, b.v);
                }
                int cc = t * 16 + l15;
                float bb = mb1[cc];
#pragma unroll
                for (int reg = 0; reg < 4; ++reg)
                    hid_s[(srow0 + quad * 4 + reg) * 136 + cc] = f2b(fmaxf(a[reg] + bb, 0.0f));
            }
        }
        {
            FragU hf[4];
#pragma unroll
            for (int ks = 0; ks < 4; ++ks)
                hf[ks].u = *(const uint4*)(hid_s + (srow0 + l15) * 136 + ks * 32 + quad * 8);
#pragma unroll 1
            for (int t = 0; t < 8; ++t) {
                f32x4 a = {0};
#pragma unroll
                for (int ks = 0; ks < 4; ++ks) {
                    FragU b; b.u = *(const uint4*)(ws + OFF_MW2T + (t * 16 + l15) * 128 + ks * 32 + quad * 8);
                    MFMA(a, hf[ks].v, b.v);
                }
                int cc = t * 16 + l15;
                float bb = mb2[cc];
#pragma unroll
                for (int reg = 0; reg < 4; ++reg)
                    slots_s[(srow0 + quad * 4 + reg) * 132 + cc] += a[reg] + bb;
            }
        }
    }

    // ---- F.normalize + store (wave-local; no barrier needed) ----
    {
        const float* rowp = slots_s + (srow0 + l15) * 132;
        float a0 = 0, a1 = 0, a2 = 0, a3 = 0;
#pragma unroll
        for (int j = 0; j < 8; ++j) {
            float x0 = rowp[quad + 16 * j];      a0 = fmaf(x0, x0, a0);
            float x1 = rowp[quad + 16 * j + 4];  a1 = fmaf(x1, x1, a1);
            float x2 = rowp[quad + 16 * j + 8];  a2 = fmaf(x2, x2, a2);
            float x3 = rowp[quad + 16 * j + 12]; a3 = fmaf(x3, x3, a3);
        }
        float ss = (a0 + a1) + (a2 + a3);
        ss += __shfl_xor(ss, 16); ss += __shfl_xor(ss, 32);
        if (quad == 0) rs_s[srow0 + l15] = 1.0f / fmaxf(sqrtf(ss), 1e-8f);
    }
    {
        size_t base = (size_t)(r0 + g) * 2048;
        for (int i4 = lane; i4 < 512; i4 += 64) {
            int row = i4 >> 5, c4 = i4 & 31;
            float4 vv = *((const float4*)(slots_s + (srow0 + row) * 132) + c4);
            float r = rs_s[srow0 + row];
            vv.x *= r; vv.y *= r; vv.z *= r; vv.w *= r;
            *((float4*)(out + base) + i4) = vv;
        }
    }
}

// ---------------- temporal chain: one block (one wave) per batch row, 63 steps ----------------
__global__ __launch_bounds__(64) void temporal2_kernel(
    const u16* __restrict__ ws, float* __restrict__ out)
{
    __shared__ __align__(16) u16 wt_s[128 * 136];
    __shared__ __align__(16) u16 prev_s[16 * 136];
    __shared__ __align__(16) float sa_s[16 * 132];

    const int lane = threadIdx.x;
    const int l15 = lane & 15, quad = lane >> 4;
    const int b = blockIdx.x;

    for (int idx = lane; idx < 2048; idx += 64) {
        int row = idx >> 4, ch = idx & 15;
        *(uint4*)(wt_s + row * 136 + ch * 8) = *(const uint4*)(ws + OFF_WTT + row * 128 + ch * 8);
    }
    {
        size_t base0 = (size_t)b * 64 * 2048;
        for (int i4 = lane; i4 < 512; i4 += 64) {
            float4 vv = *((const float4*)(out + base0) + i4);
            int row = i4 >> 5, c0 = (i4 & 31) * 4;
            ushort4 pk;
            pk.x = f2b(vv.x); pk.y = f2b(vv.y); pk.z = f2b(vv.z); pk.w = f2b(vv.w);
            *(ushort4*)(prev_s + row * 136 + c0) = pk;
        }
    }
    // single wave: LDS ordering within a wave is handled by waitcnts; no barriers needed

    for (int t = 1; t < 64; ++t) {
        size_t base = ((size_t)b * 64 + t) * 2048;
        FragU ap[4];
#pragma unroll
        for (int ks = 0; ks < 4; ++ks)
            ap[ks].u = *(const uint4*)(prev_s + l15 * 136 + ks * 32 + quad * 8);
        for (int i4 = lane; i4 < 512; i4 += 64) {
            float4 vv = *((const float4*)(out + base) + i4);
            *((float4*)(sa_s + (i4 >> 5) * 132) + (i4 & 31)) = vv;
        }
        f32x4 acc[8] = {{0}, {0}, {0}, {0}, {0}, {0}, {0}, {0}};
#pragma unroll
        for (int tt = 0; tt < 8; ++tt) {
#pragma unroll
            for (int ks = 0; ks < 4; ++ks) {
                FragU bv; bv.u = *(const uint4*)(wt_s + (tt * 16 + l15) * 136 + ks * 32 + quad * 8);
                MFMA(acc[tt], ap[ks].v, bv.v);
            }
        }
#pragma unroll
        for (int tt = 0; tt < 8; ++tt) {
            int col = tt * 16 + l15;
#pragma unroll
            for (int reg = 0; reg < 4; ++reg) {
                int row = quad * 4 + reg;
                float bl = 0.7f * sa_s[row * 132 + col] + 0.3f * tanhf(acc[tt][reg]);
                out[base + row * 128 + col] = bl;
                prev_s[row * 136 + col] = f2b(bl);
            }
        }
    }
}

extern "C" void kernel_launch(void* const* d_in, const int* in_sizes, int n_in,
                              void* d_out, int out_size, void* d_ws, size_t ws_size,
                              hipStream_t stream) {
    const float* obs   = (const float*)d_in[0];
    const float* eW1   = (const float*)d_in[1];
    const float* eb1   = (const float*)d_in[2];
    const float* eW2   = (const float*)d_in[3];
    const float* eb2   = (const float*)d_in[4];
    const float* skipW = (const float*)d_in[5];
    const float* smu   = (const float*)d_in[6];
    const float* Wk    = (const float*)d_in[7];
    const float* Wv    = (const float*)d_in[8];
    const float* Wq    = (const float*)d_in[9];
    const float* Wih   = (const float*)d_in[10];
    const float* Whh   = (const float*)d_in[11];
    const float* bih   = (const float*)d_in[12];
    const float* bhh   = (const float*)d_in[13];
    const float* mW1   = (const float*)d_in[14];
    const float* mb1   = (const float*)d_in[15];
    const float* mW2   = (const float*)d_in[16];
    const float* mb2   = (const float*)d_in[17];
    const float* g_in  = (const float*)d_in[18];
    const float* be_in = (const float*)d_in[19];
    const float* g_sl  = (const float*)d_in[20];
    const float* be_sl = (const float*)d_in[21];
    const float* g_ml  = (const float*)d_in[22];
    const float* be_ml = (const float*)d_in[23];
    const float* Wt    = (const float*)d_in[24];
    float* out = (float*)d_out;
    u16* ws = (u16*)d_ws;

    prep_kernel<<<dim3(512, 11), 256, 0, stream>>>(eW1, eW2, skipW, Wk, Wv, Wq,
                                                   Wih, Whh, mW1, mW2, Wt, ws);
    sa2_kernel<<<B_ * T_ / 4, 256, 0, stream>>>(obs, eb1, eb2, smu, bih, bhh, mb1, mb2,
                                                g_in, be_in, g_sl, be_sl, g_ml, be_ml,
                                                ws, out);
    temporal2_kernel<<<B_, 64, 0, stream>>>(ws, out);
}

// Round 6
// 1808.276 us; speedup vs baseline: 1.7620x; 1.2617x over previous
//
#include <hip/hip_runtime.h>
#include <math.h>

#define B_ 256
#define T_ 64
#define DOBS 512
#define D_ 128
#define N_ 16
#define H_ 256

typedef unsigned short u16;
typedef short bf16x8 __attribute__((ext_vector_type(8)));
typedef float f32x4 __attribute__((ext_vector_type(4)));

union FragU { bf16x8 v; uint4 u; };

#define MFMA(ACC, A, Bv) (ACC) = __builtin_amdgcn_mfma_f32_16x16x32_bf16((A), (Bv), (ACC), 0, 0, 0)
#define MFMA2(ACC, AH, AL, Bv) do { MFMA(ACC, AH, Bv); MFMA(ACC, AL, Bv); } while (0)

// ws layout (u16 elements), all matrices transposed to [n][k] bf16:
#define OFF_EW1T   0        // 256x512
#define OFF_EW2T   131072   // 128x256
#define OFF_SKIPT  163840   // 128x512
#define OFF_WKVT   229376   // 256x128 (rows 0-127 Wk, 128-255 Wv)
#define OFF_WQT    262144   // 128x128
#define OFF_WIHT   278528   // 384x128
#define OFF_WHHT   327680   // 384x128
#define OFF_MW1T   376832   // 128x128
#define OFF_MW2T   393216   // 128x128
#define OFF_WTT    409600   // 128x128

__device__ __forceinline__ unsigned rne16(float f) {
    unsigned u = __float_as_uint(f);
    return (u + 0x7FFFu + ((u >> 16) & 1u)) >> 16;
}
__device__ __forceinline__ float fromhi(unsigned h) { return __uint_as_float(h << 16); }
__device__ __forceinline__ u16 f2b(float f) { return (u16)rne16(f); }
__device__ __forceinline__ float sigmoidf_(float x) { return 1.0f / (1.0f + expf(-x)); }

__device__ __forceinline__ void mk_pack(const float* x, FragU& fh, FragU& fl) {
    unsigned h[8], l[8];
#pragma unroll
    for (int j = 0; j < 8; ++j) {
        h[j] = rne16(x[j]);
        l[j] = rne16(x[j] - fromhi(h[j]));
    }
    fh.u = make_uint4(h[0] | (h[1] << 16), h[2] | (h[3] << 16), h[4] | (h[5] << 16), h[6] | (h[7] << 16));
    fl.u = make_uint4(l[0] | (l[1] << 16), l[2] | (l[3] << 16), l[4] | (l[5] << 16), l[6] | (l[7] << 16));
}

__device__ __forceinline__ void mk_raw(const float* p, FragU& fh, FragU& fl) {
    float4 a = *(const float4*)p, b = *(const float4*)(p + 4);
    float x[8] = {a.x, a.y, a.z, a.w, b.x, b.y, b.z, b.w};
    mk_pack(x, fh, fl);
}

__device__ __forceinline__ void mk_aff(const float* p, float mu, float rs,
                                       const float* gp, const float* bp,
                                       FragU& fh, FragU& fl) {
    float4 a = *(const float4*)p, b = *(const float4*)(p + 4);
    float4 g0 = *(const float4*)gp, g1 = *(const float4*)(gp + 4);
    float4 b0 = *(const float4*)bp, b1 = *(const float4*)(bp + 4);
    float x[8];
    x[0] = (a.x - mu) * rs * g0.x + b0.x;  x[1] = (a.y - mu) * rs * g0.y + b0.y;
    x[2] = (a.z - mu) * rs * g0.z + b0.z;  x[3] = (a.w - mu) * rs * g0.w + b0.w;
    x[4] = (b.x - mu) * rs * g1.x + b1.x;  x[5] = (b.y - mu) * rs * g1.y + b1.y;
    x[6] = (b.z - mu) * rs * g1.z + b1.z;  x[7] = (b.w - mu) * rs * g1.w + b1.w;
    mk_pack(x, fh, fl);
}

__device__ __forceinline__ void mk_scaled(const float* p, float sc, FragU& fh, FragU& fl) {
    float4 a = *(const float4*)p, b = *(const float4*)(p + 4);
    float x[8] = {sc * a.x, sc * a.y, sc * a.z, sc * a.w, sc * b.x, sc * b.y, sc * b.z, sc * b.w};
    mk_pack(x, fh, fl);
}

// ---------------- weight prepass: fp32 [k][n] -> bf16 [n][k] ----------------
__global__ __launch_bounds__(256) void prep_kernel(
    const float* __restrict__ eW1, const float* __restrict__ eW2, const float* __restrict__ skipW,
    const float* __restrict__ Wk, const float* __restrict__ Wv, const float* __restrict__ Wq,
    const float* __restrict__ Wih, const float* __restrict__ Whh,
    const float* __restrict__ mW1, const float* __restrict__ mW2, const float* __restrict__ Wt,
    u16* __restrict__ ws)
{
    int id = blockIdx.y;
    const float* src; int dstoff, logk, N;
    switch (id) {
        case 0:  src = eW1;   dstoff = OFF_EW1T;  logk = 9; N = 256; break;
        case 1:  src = eW2;   dstoff = OFF_EW2T;  logk = 8; N = 128; break;
        case 2:  src = skipW; dstoff = OFF_SKIPT; logk = 9; N = 128; break;
        case 3:  src = Wk;    dstoff = OFF_WKVT;  logk = 7; N = 128; break;
        case 4:  src = Wv;    dstoff = OFF_WKVT + 16384; logk = 7; N = 128; break;
        case 5:  src = Wq;    dstoff = OFF_WQT;   logk = 7; N = 128; break;
        case 6:  src = Wih;   dstoff = OFF_WIHT;  logk = 7; N = 384; break;
        case 7:  src = Whh;   dstoff = OFF_WHHT;  logk = 7; N = 384; break;
        case 8:  src = mW1;   dstoff = OFF_MW1T;  logk = 7; N = 128; break;
        case 9:  src = mW2;   dstoff = OFF_MW2T;  logk = 7; N = 128; break;
        default: src = Wt;    dstoff = OFF_WTT;   logk = 7; N = 128; break;
    }
    int idx = blockIdx.x * 256 + threadIdx.x;
    int K = 1 << logk;
    if (idx < K * N) {
        int n = idx >> logk, k = idx & (K - 1);
        ws[dstoff + idx] = f2b(src[k * N + n]);
    }
}

// ---------------- main fused kernel: 4 (b,t) rows per block ----------------
__global__ __launch_bounds__(256) void sa2_kernel(
    const float* __restrict__ obs,
    const float* __restrict__ eb1, const float* __restrict__ eb2,
    const float* __restrict__ slot_mu,
    const float* __restrict__ bih, const float* __restrict__ bhh,
    const float* __restrict__ mb1, const float* __restrict__ mb2,
    const float* __restrict__ g_in, const float* __restrict__ be_in,
    const float* __restrict__ g_sl, const float* __restrict__ be_sl,
    const float* __restrict__ g_ml, const float* __restrict__ be_ml,
    const u16* __restrict__ ws, float* __restrict__ out)
{
    __shared__ __align__(16) float slots_s[64 * 132];      // 33792 B
    __shared__ __align__(16) float scratch[4352];          // enc: obs(4x516)+h(4x260)+z(4x132); iter: hid u16 4x16x136
    __shared__ __align__(16) float k_s[4 * 132];
    __shared__ __align__(16) float v_s[4 * 132];
    __shared__ __align__(16) float par_s[6 * 128];         // gin, bin, gsl, bsl, gml, bml
    __shared__ __align__(16) float bias_s[512];            // b_rz[256], bin_[128], bhn_[128]
    __shared__ __align__(16) float gv_s[4 * 392];          // per-row v@Wih (384) padded
    __shared__ float rs_s[64];
    __shared__ float logit_s[64];
    __shared__ float zmu_s[4], zrs_s[4];

    float* obs_s = scratch;            // 4 x 516
    float* h_s   = scratch + 2064;     // 4 x 260
    float* z_s   = scratch + 3104;     // 4 x 132
    u16*   hid_s = (u16*)scratch;      // 4 groups x 16 x 136 (iter phase)

    const int tid = threadIdx.x;
    const int wave = tid >> 6, lane = tid & 63;
    const int l15 = lane & 15, quad = lane >> 4;
    const int r0 = blockIdx.x * 4;

    // ---- stage params / biases / obs ----
    if (tid < 128) {
        par_s[tid]       = g_in[tid];  par_s[128 + tid] = be_in[tid];
        par_s[256 + tid] = g_sl[tid];  par_s[384 + tid] = be_sl[tid];
        par_s[512 + tid] = g_ml[tid];  par_s[640 + tid] = be_ml[tid];
        bias_s[256 + tid] = bih[256 + tid];
        bias_s[384 + tid] = bhh[256 + tid];
    }
    if (tid < 256) bias_s[tid] = bih[tid] + bhh[tid];
    for (int i4 = tid; i4 < 512; i4 += 256) {
        int g2 = i4 >> 7, c4 = i4 & 127;
        *((float4*)(obs_s + g2 * 516) + c4) = *((const float4*)(obs + (size_t)(r0 + g2) * 512) + c4);
    }
    __syncthreads();

    // ---- encoder layer 1: h = gelu(obs@W1 + b1); M-tile has rows 0-3 valid ----
    {
        f32x4 acc[4] = {{0}, {0}, {0}, {0}};
        const float* abase = obs_s + (l15 & 3) * 516;
#pragma unroll 1
        for (int ks = 0; ks < 16; ++ks) {
            FragU ah, al;
            mk_raw(abase + ks * 32 + quad * 8, ah, al);
#pragma unroll
            for (int tt = 0; tt < 4; ++tt) {
                int row = (wave * 4 + tt) * 16 + l15;
                FragU b; b.u = *(const uint4*)(ws + OFF_EW1T + row * 512 + ks * 32 + quad * 8);
                MFMA2(acc[tt], ah.v, al.v, b.v);
            }
        }
        {
            f32x4 av = acc[0];
            if (quad == 1) av = acc[1];
            if (quad == 2) av = acc[2];
            if (quad == 3) av = acc[3];
            int col = (wave * 4 + quad) * 16 + l15;
            float bb = eb1[col];
#pragma unroll
            for (int reg = 0; reg < 4; ++reg) {
                float x = av[reg] + bb;
                h_s[reg * 260 + col] = 0.5f * x * (1.0f + erff(x * 0.7071067811865475f));
            }
        }
    }
    __syncthreads();

    // ---- z = tanh(h@W2 + b2 + obs@skip) ----
    {
        f32x4 acc[2] = {{0}, {0}};
        const float* hbase = h_s + (l15 & 3) * 260;
#pragma unroll 1
        for (int ks = 0; ks < 8; ++ks) {
            FragU ah, al;
            mk_raw(hbase + ks * 32 + quad * 8, ah, al);
#pragma unroll
            for (int tt = 0; tt < 2; ++tt) {
                int row = (wave * 2 + tt) * 16 + l15;
                FragU b; b.u = *(const uint4*)(ws + OFF_EW2T + row * 256 + ks * 32 + quad * 8);
                MFMA2(acc[tt], ah.v, al.v, b.v);
            }
        }
        const float* obase = obs_s + (l15 & 3) * 516;
#pragma unroll 1
        for (int ks = 0; ks < 16; ++ks) {
            FragU ah, al;
            mk_raw(obase + ks * 32 + quad * 8, ah, al);
#pragma unroll
            for (int tt = 0; tt < 2; ++tt) {
                int row = (wave * 2 + tt) * 16 + l15;
                FragU b; b.u = *(const uint4*)(ws + OFF_SKIPT + row * 512 + ks * 32 + quad * 8);
                MFMA2(acc[tt], ah.v, al.v, b.v);
            }
        }
        if (quad < 2) {
            f32x4 av = (quad == 0) ? acc[0] : acc[1];
            int col = (wave * 2 + quad) * 16 + l15;
            float bb = eb2[col];
#pragma unroll
            for (int reg = 0; reg < 4; ++reg)
                z_s[reg * 132 + col] = tanhf(av[reg] + bb);
        }
    }
    __syncthreads();

    // ---- LN(z) stats: wave w computes row w stats ----
    {
        const float* row = z_s + wave * 132;
        float x0 = row[lane], x1 = row[64 + lane];
        float s = x0 + x1;
        s += __shfl_xor(s, 1);  s += __shfl_xor(s, 2);  s += __shfl_xor(s, 4);
        s += __shfl_xor(s, 8);  s += __shfl_xor(s, 16); s += __shfl_xor(s, 32);
        float mu = s * (1.0f / 128.0f);
        float d0 = x0 - mu, d1 = x1 - mu;
        float v = fmaf(d0, d0, d1 * d1);
        v += __shfl_xor(v, 1);  v += __shfl_xor(v, 2);  v += __shfl_xor(v, 4);
        v += __shfl_xor(v, 8);  v += __shfl_xor(v, 16); v += __shfl_xor(v, 32);
        if (lane == 0) { zmu_s[wave] = mu; zrs_s[wave] = rsqrtf(v * (1.0f / 128.0f) + 1e-5f); }
    }
    __syncthreads();

    // ---- k,v = LN(z) @ [Wk|Wv] ----
    {
        f32x4 acc[4] = {{0}, {0}, {0}, {0}};
        const float* zbase = z_s + (l15 & 3) * 132;
        float zmu = zmu_s[l15 & 3], zrs = zrs_s[l15 & 3];
#pragma unroll 1
        for (int ks = 0; ks < 4; ++ks) {
            FragU ah, al;
            mk_aff(zbase + ks * 32 + quad * 8, zmu, zrs,
                   par_s + ks * 32 + quad * 8, par_s + 128 + ks * 32 + quad * 8, ah, al);
#pragma unroll
            for (int tt = 0; tt < 4; ++tt) {
                int row = (wave * 4 + tt) * 16 + l15;
                FragU b; b.u = *(const uint4*)(ws + OFF_WKVT + row * 128 + ks * 32 + quad * 8);
                MFMA2(acc[tt], ah.v, al.v, b.v);
            }
        }
        {
            f32x4 av = acc[0];
            if (quad == 1) av = acc[1];
            if (quad == 2) av = acc[2];
            if (quad == 3) av = acc[3];
            int col = (wave * 4 + quad) * 16 + l15;
#pragma unroll
            for (int reg = 0; reg < 4; ++reg) {
                if (col < 128) k_s[reg * 132 + col] = av[reg];
                else           v_s[reg * 132 + col - 128] = av[reg];
            }
        }
    }
    __syncthreads();

    // ---- GV precompute: gv[r][j] = sum_d v[r][d] * Wih[d][j]  (j in [0,384)) ----
    // Same fragment structure as the kv phase above; 6 column blocks per wave.
    {
        f32x4 ag[6] = {{0}, {0}, {0}, {0}, {0}, {0}};
        const float* vbase = v_s + (l15 & 3) * 132;
#pragma unroll 1
        for (int ks = 0; ks < 4; ++ks) {
            FragU ah, al;
            mk_raw(vbase + ks * 32 + quad * 8, ah, al);
#pragma unroll
            for (int tt = 0; tt < 6; ++tt) {
                int row = (wave * 6 + tt) * 16 + l15;
                FragU b; b.u = *(const uint4*)(ws + OFF_WIHT + row * 128 + ks * 32 + quad * 8);
                MFMA2(ag[tt], ah.v, al.v, b.v);
            }
        }
        // Every quad's acc holds data rows 0-3 (A rows are (l15&3)-replicated);
        // quad q writes blocks tt with tt%4 == q -> blocks {q, q+4} cover tt=0..5.
#pragma unroll
        for (int tt = 0; tt < 6; ++tt) {
            if ((tt & 3) == quad) {
                int col = (wave * 6 + tt) * 16 + l15;
#pragma unroll
                for (int reg = 0; reg < 4; ++reg)
                    gv_s[reg * 392 + col] = ag[tt][reg];
            }
        }
    }
    __syncthreads();   // gv_s written by all waves -> read by all in iter loop

    // ---- slot loop: wave w owns group g=w ----
    const int g = wave;
    const int srow0 = g * 16;
    for (int i4 = lane; i4 < 512; i4 += 64) {
        int row = i4 >> 5, c4 = i4 & 31;
        *((float4*)(slots_s + (srow0 + row) * 132) + c4) = *((const float4*)slot_mu + i4);
    }
    const float* gvrow = gv_s + g * 392;

    for (int iter = 0; iter < 3; ++iter) {
        // LN stats of own row (l15); strided-4 reads, 4 partial sums
        float myMu, myRs;
        {
            const float* rowp = slots_s + (srow0 + l15) * 132;
            float s0 = 0, s1 = 0, s2 = 0, s3 = 0;
#pragma unroll
            for (int j = 0; j < 8; ++j) {
                s0 += rowp[quad + 16 * j];
                s1 += rowp[quad + 16 * j + 4];
                s2 += rowp[quad + 16 * j + 8];
                s3 += rowp[quad + 16 * j + 12];
            }
            float s = (s0 + s1) + (s2 + s3);
            s += __shfl_xor(s, 16); s += __shfl_xor(s, 32);
            myMu = s * (1.0f / 128.0f);
            float v0 = 0, v1 = 0, v2 = 0, v3 = 0;
#pragma unroll
            for (int j = 0; j < 8; ++j) {
                float d0 = rowp[quad + 16 * j] - myMu;      v0 = fmaf(d0, d0, v0);
                float d1 = rowp[quad + 16 * j + 4] - myMu;  v1 = fmaf(d1, d1, v1);
                float d2 = rowp[quad + 16 * j + 8] - myMu;  v2 = fmaf(d2, d2, v2);
                float d3 = rowp[quad + 16 * j + 12] - myMu; v3 = fmaf(d3, d3, v3);
            }
            float v = (v0 + v1) + (v2 + v3);
            v += __shfl_xor(v, 16); v += __shfl_xor(v, 32);
            myRs = rsqrtf(v * (1.0f / 128.0f) + 1e-5f);
        }

        // ---- q = LN(slots)@Wq fused with logits ----
        {
            FragU ah[4], al[4];
#pragma unroll
            for (int ks = 0; ks < 4; ++ks)
                mk_aff(slots_s + (srow0 + l15) * 132 + ks * 32 + quad * 8, myMu, myRs,
                       par_s + 256 + ks * 32 + quad * 8, par_s + 384 + ks * 32 + quad * 8,
                       ah[ks], al[ks]);
            float lp[4] = {0, 0, 0, 0};
#pragma unroll 1
            for (int t = 0; t < 8; ++t) {
                f32x4 a = {0};
#pragma unroll
                for (int ks = 0; ks < 4; ++ks) {
                    FragU b; b.u = *(const uint4*)(ws + OFF_WQT + (t * 16 + l15) * 128 + ks * 32 + quad * 8);
                    MFMA2(a, ah[ks].v, al[ks].v, b.v);
                }
                float kc = k_s[g * 132 + t * 16 + l15];
#pragma unroll
                for (int reg = 0; reg < 4; ++reg) lp[reg] = fmaf(a[reg], kc, lp[reg]);
            }
#pragma unroll
            for (int reg = 0; reg < 4; ++reg) {
                lp[reg] += __shfl_xor(lp[reg], 1);
                lp[reg] += __shfl_xor(lp[reg], 2);
                lp[reg] += __shfl_xor(lp[reg], 4);
                lp[reg] += __shfl_xor(lp[reg], 8);
            }
            if (l15 == 0) {
#pragma unroll
                for (int reg = 0; reg < 4; ++reg)
                    logit_s[srow0 + quad * 4 + reg] = lp[reg] * 0.08838834764831845f;
            }
        }

        // softmax over 16 slots: shuffle reduce within 16-lane group
        float attn_me;
        {
            float x = logit_s[srow0 + l15];
            float mx = fmaxf(x, __shfl_xor(x, 1));
            mx = fmaxf(mx, __shfl_xor(mx, 2));
            mx = fmaxf(mx, __shfl_xor(mx, 4));
            mx = fmaxf(mx, __shfl_xor(mx, 8));
            float e = expf(x - mx);
            float den = e;
            den += __shfl_xor(den, 1);
            den += __shfl_xor(den, 2);
            den += __shfl_xor(den, 4);
            den += __shfl_xor(den, 8);
            attn_me = e / den;
        }

        // ---- GRU: gh = slots@Whh via MFMA; gi = attn * gv (folded, scalar) ----
        {
            float attn_r[4];
#pragma unroll
            for (int reg = 0; reg < 4; ++reg) attn_r[reg] = __shfl(attn_me, quad * 4 + reg);
            FragU ash[4], asl[4];
#pragma unroll
            for (int ks = 0; ks < 4; ++ks)
                mk_raw(slots_s + (srow0 + l15) * 132 + ks * 32 + quad * 8, ash[ks], asl[ks]);
#pragma unroll 1
            for (int cg = 0; cg < 8; ++cg) {
                f32x4 ar = {0}, az = {0}, anh = {0};
                const int rowb = cg * 16 + l15;
#pragma unroll
                for (int ks = 0; ks < 4; ++ks) {
                    const int koff = ks * 32 + quad * 8;
                    FragU b;
                    b.u = *(const uint4*)(ws + OFF_WHHT + rowb * 128 + koff);
                    MFMA2(ar, ash[ks].v, asl[ks].v, b.v);
                    b.u = *(const uint4*)(ws + OFF_WHHT + (128 + rowb) * 128 + koff);
                    MFMA2(az, ash[ks].v, asl[ks].v, b.v);
                    b.u = *(const uint4*)(ws + OFF_WHHT + (256 + rowb) * 128 + koff);
                    MFMA2(anh, ash[ks].v, asl[ks].v, b.v);
                }
                const int cc = cg * 16 + l15;
                float gvr = gvrow[cc], gvz = gvrow[128 + cc], gvn = gvrow[256 + cc];
#pragma unroll
                for (int reg = 0; reg < 4; ++reg) {
                    int row = srow0 + quad * 4 + reg;
                    float a = attn_r[reg];
                    float rg = sigmoidf_(fmaf(a, gvr, ar[reg] + bias_s[cc]));
                    float zg = sigmoidf_(fmaf(a, gvz, az[reg] + bias_s[128 + cc]));
                    float ng = tanhf(fmaf(a, gvn, bias_s[256 + cc]) + rg * (anh[reg] + bias_s[384 + cc]));
                    float hp = slots_s[row * 132 + cc];
                    slots_s[row * 132 + cc] = (1.0f - zg) * ng + zg * hp;
                }
            }
        }

        // ---- MLP: slots += relu(LN(slots)@W1+b1)@W2+b2 ----
        {
            const float* rowp = slots_s + (srow0 + l15) * 132;
            float s0 = 0, s1 = 0, s2 = 0, s3 = 0;
#pragma unroll
            for (int j = 0; j < 8; ++j) {
                s0 += rowp[quad + 16 * j];
                s1 += rowp[quad + 16 * j + 4];
                s2 += rowp[quad + 16 * j + 8];
                s3 += rowp[quad + 16 * j + 12];
            }
            float s = (s0 + s1) + (s2 + s3);
            s += __shfl_xor(s, 16); s += __shfl_xor(s, 32);
            float mu2 = s * (1.0f / 128.0f);
            float v0 = 0, v1 = 0, v2 = 0, v3 = 0;
#pragma unroll
            for (int j = 0; j < 8; ++j) {
                float d0 = rowp[quad + 16 * j] - mu2;      v0 = fmaf(d0, d0, v0);
                float d1 = rowp[quad + 16 * j + 4] - mu2;  v1 = fmaf(d1, d1, v1);
                float d2 = rowp[quad + 16 * j + 8] - mu2;  v2 = fmaf(d2, d2, v2);
                float d3 = rowp[quad + 16 * j + 12] - mu2; v3 = fmaf(d3, d3, v3);
            }
            float v = (v0 + v1) + (v2 + v3);
            v += __shfl_xor(v, 16); v += __shfl_xor(v, 32);
            float rs2 = rsqrtf(v * (1.0f / 128.0f) + 1e-5f);

            FragU ah[4], al[4];
#pragma unroll
            for (int ks = 0; ks < 4; ++ks)
                mk_aff(rowp + ks * 32 + quad * 8, mu2, rs2,
                       par_s + 512 + ks * 32 + quad * 8, par_s + 640 + ks * 32 + quad * 8,
                       ah[ks], al[ks]);
#pragma unroll 1
            for (int t = 0; t < 8; ++t) {
                f32x4 a = {0};
#pragma unroll
                for (int ks = 0; ks < 4; ++ks) {
                    FragU b; b.u = *(const uint4*)(ws + OFF_MW1T + (t * 16 + l15) * 128 + ks * 32 + quad * 8);
                    MFMA2(a, ah[ks].v, al[ks].v, b.v);
                }
                int cc = t * 16 + l15;
                float bb = mb1[cc];
#pragma unroll
                for (int reg = 0; reg < 4; ++reg)
                    hid_s[(srow0 + quad * 4 + reg) * 136 + cc] = f2b(fmaxf(a[reg] + bb, 0.0f));
            }
        }
        {
            FragU hf[4];
#pragma unroll
            for (int ks = 0; ks < 4; ++ks)
                hf[ks].u = *(const uint4*)(hid_s + (srow0 + l15) * 136 + ks * 32 + quad * 8);
#pragma unroll 1
            for (int t = 0; t < 8; ++t) {
                f32x4 a = {0};
#pragma unroll
                for (int ks = 0; ks < 4; ++ks) {
                    FragU b; b.u = *(const uint4*)(ws + OFF_MW2T + (t * 16 + l15) * 128 + ks * 32 + quad * 8);
                    MFMA(a, hf[ks].v, b.v);
                }
                int cc = t * 16 + l15;
                float bb = mb2[cc];
#pragma unroll
                for (int reg = 0; reg < 4; ++reg)
                    slots_s[(srow0 + quad * 4 + reg) * 132 + cc] += a[reg] + bb;
            }
        }
    }

    // ---- F.normalize + store (wave-local) ----
    {
        const float* rowp = slots_s + (srow0 + l15) * 132;
        float a0 = 0, a1 = 0, a2 = 0, a3 = 0;
#pragma unroll
        for (int j = 0; j < 8; ++j) {
            float x0 = rowp[quad + 16 * j];      a0 = fmaf(x0, x0, a0);
            float x1 = rowp[quad + 16 * j + 4];  a1 = fmaf(x1, x1, a1);
            float x2 = rowp[quad + 16 * j + 8];  a2 = fmaf(x2, x2, a2);
            float x3 = rowp[quad + 16 * j + 12]; a3 = fmaf(x3, x3, a3);
        }
        float ss = (a0 + a1) + (a2 + a3);
        ss += __shfl_xor(ss, 16); ss += __shfl_xor(ss, 32);
        if (quad == 0) rs_s[srow0 + l15] = 1.0f / fmaxf(sqrtf(ss), 1e-8f);
    }
    {
        size_t base = (size_t)(r0 + g) * 2048;
        for (int i4 = lane; i4 < 512; i4 += 64) {
            int row = i4 >> 5, c4 = i4 & 31;
            float4 vv = *((const float4*)(slots_s + (srow0 + row) * 132) + c4);
            float r = rs_s[srow0 + row];
            vv.x *= r; vv.y *= r; vv.z *= r; vv.w *= r;
            *((float4*)(out + base) + i4) = vv;
        }
    }
}

// ---------------- temporal chain: one block (one wave) per batch row, 63 steps ----------------
__global__ __launch_bounds__(64) void temporal2_kernel(
    const u16* __restrict__ ws, float* __restrict__ out)
{
    __shared__ __align__(16) u16 wt_s[128 * 136];
    __shared__ __align__(16) u16 prev_s[16 * 136];
    __shared__ __align__(16) float sa_s[16 * 132];

    const int lane = threadIdx.x;
    const int l15 = lane & 15, quad = lane >> 4;
    const int b = blockIdx.x;

    for (int idx = lane; idx < 2048; idx += 64) {
        int row = idx >> 4, ch = idx & 15;
        *(uint4*)(wt_s + row * 136 + ch * 8) = *(const uint4*)(ws + OFF_WTT + row * 128 + ch * 8);
    }
    {
        size_t base0 = (size_t)b * 64 * 2048;
        for (int i4 = lane; i4 < 512; i4 += 64) {
            float4 vv = *((const float4*)(out + base0) + i4);
            int row = i4 >> 5, c0 = (i4 & 31) * 4;
            ushort4 pk;
            pk.x = f2b(vv.x); pk.y = f2b(vv.y); pk.z = f2b(vv.z); pk.w = f2b(vv.w);
            *(ushort4*)(prev_s + row * 136 + c0) = pk;
        }
    }

    for (int t = 1; t < 64; ++t) {
        size_t base = ((size_t)b * 64 + t) * 2048;
        __syncthreads();
        FragU ap[4];
#pragma unroll
        for (int ks = 0; ks < 4; ++ks)
            ap[ks].u = *(const uint4*)(prev_s + l15 * 136 + ks * 32 + quad * 8);
        for (int i4 = lane; i4 < 512; i4 += 64) {
            float4 vv = *((const float4*)(out + base) + i4);
            *((float4*)(sa_s + (i4 >> 5) * 132) + (i4 & 31)) = vv;
        }
        f32x4 acc[8] = {{0}, {0}, {0}, {0}, {0}, {0}, {0}, {0}};
#pragma unroll
        for (int tt = 0; tt < 8; ++tt) {
#pragma unroll
            for (int ks = 0; ks < 4; ++ks) {
                FragU bv; bv.u = *(const uint4*)(wt_s + (tt * 16 + l15) * 136 + ks * 32 + quad * 8);
                MFMA(acc[tt], ap[ks].v, bv.v);
            }
        }
        __syncthreads();
#pragma unroll
        for (int tt = 0; tt < 8; ++tt) {
            int col = tt * 16 + l15;
#pragma unroll
            for (int reg = 0; reg < 4; ++reg) {
                int row = quad * 4 + reg;
                float bl = 0.7f * sa_s[row * 132 + col] + 0.3f * tanhf(acc[tt][reg]);
                out[base + row * 128 + col] = bl;
                prev_s[row * 136 + col] = f2b(bl);
            }
        }
    }
}

extern "C" void kernel_launch(void* const* d_in, const int* in_sizes, int n_in,
                              void* d_out, int out_size, void* d_ws, size_t ws_size,
                              hipStream_t stream) {
    const float* obs   = (const float*)d_in[0];
    const float* eW1   = (const float*)d_in[1];
    const float* eb1   = (const float*)d_in[2];
    const float* eW2   = (const float*)d_in[3];
    const float* eb2   = (const float*)d_in[4];
    const float* skipW = (const float*)d_in[5];
    const float* smu   = (const float*)d_in[6];
    const float* Wk    = (const float*)d_in[7];
    const float* Wv    = (const float*)d_in[8];
    const float* Wq    = (const float*)d_in[9];
    const float* Wih   = (const float*)d_in[10];
    const float* Whh   = (const float*)d_in[11];
    const float* bih   = (const float*)d_in[12];
    const float* bhh   = (const float*)d_in[13];
    const float* mW1   = (const float*)d_in[14];
    const float* mb1   = (const float*)d_in[15];
    const float* mW2   = (const float*)d_in[16];
    const float* mb2   = (const float*)d_in[17];
    const float* g_in  = (const float*)d_in[18];
    const float* be_in = (const float*)d_in[19];
    const float* g_sl  = (const float*)d_in[20];
    const float* be_sl = (const float*)d_in[21];
    const float* g_ml  = (const float*)d_in[22];
    const float* be_ml = (const float*)d_in[23];
    const float* Wt    = (const float*)d_in[24];
    float* out = (float*)d_out;
    u16* ws = (u16*)d_ws;

    prep_kernel<<<dim3(512, 11), 256, 0, stream>>>(eW1, eW2, skipW, Wk, Wv, Wq,
                                                   Wih, Whh, mW1, mW2, Wt, ws);
    sa2_kernel<<<B_ * T_ / 4, 256, 0, stream>>>(obs, eb1, eb2, smu, bih, bhh, mb1, mb2,
                                                g_in, be_in, g_sl, be_sl, g_ml, be_ml,
                                                ws, out);
    temporal2_kernel<<<B_, 64, 0, stream>>>(ws, out);
}

// Round 7
// 1695.651 us; speedup vs baseline: 1.8790x; 1.0664x over previous
//
#include <hip/hip_runtime.h>
#include <math.h>

#define B_ 256
#define T_ 64
#define DOBS 512
#define D_ 128
#define N_ 16
#define H_ 256

typedef unsigned short u16;
typedef short bf16x8 __attribute__((ext_vector_type(8)));
typedef float f32x4 __attribute__((ext_vector_type(4)));

union FragU { bf16x8 v; uint4 u; };

#define MFMA(ACC, A, Bv) (ACC) = __builtin_amdgcn_mfma_f32_16x16x32_bf16((A), (Bv), (ACC), 0, 0, 0)
#define MFMA2(ACC, AH, AL, Bv) do { MFMA(ACC, AH, Bv); MFMA(ACC, AL, Bv); } while (0)

// ws layout (u16 elements), all matrices transposed to [n][k] bf16:
#define OFF_EW1T   0        // 256x512
#define OFF_EW2T   131072   // 128x256
#define OFF_SKIPT  163840   // 128x512
#define OFF_WKVT   229376   // 256x128 (rows 0-127 Wk, 128-255 Wv)
#define OFF_WIHT   278528   // 384x128
#define OFF_WHHT   327680   // 384x128
#define OFF_MW1T   376832   // 128x128
#define OFF_MW2T   393216   // 128x128
#define OFF_WTT    409600   // 128x128

__device__ __forceinline__ unsigned rne16(float f) {
    unsigned u = __float_as_uint(f);
    return (u + 0x7FFFu + ((u >> 16) & 1u)) >> 16;
}
__device__ __forceinline__ float fromhi(unsigned h) { return __uint_as_float(h << 16); }
__device__ __forceinline__ u16 f2b(float f) { return (u16)rne16(f); }
__device__ __forceinline__ float sigmoidf_(float x) { return 1.0f / (1.0f + expf(-x)); }

__device__ __forceinline__ void mk_pack(const float* x, FragU& fh, FragU& fl) {
    unsigned h[8], l[8];
#pragma unroll
    for (int j = 0; j < 8; ++j) {
        h[j] = rne16(x[j]);
        l[j] = rne16(x[j] - fromhi(h[j]));
    }
    fh.u = make_uint4(h[0] | (h[1] << 16), h[2] | (h[3] << 16), h[4] | (h[5] << 16), h[6] | (h[7] << 16));
    fl.u = make_uint4(l[0] | (l[1] << 16), l[2] | (l[3] << 16), l[4] | (l[5] << 16), l[6] | (l[7] << 16));
}

__device__ __forceinline__ void mk_raw(const float* p, FragU& fh, FragU& fl) {
    float4 a = *(const float4*)p, b = *(const float4*)(p + 4);
    float x[8] = {a.x, a.y, a.z, a.w, b.x, b.y, b.z, b.w};
    mk_pack(x, fh, fl);
}

__device__ __forceinline__ void mk_aff(const float* p, float mu, float rs,
                                       const float* gp, const float* bp,
                                       FragU& fh, FragU& fl) {
    float4 a = *(const float4*)p, b = *(const float4*)(p + 4);
    float4 g0 = *(const float4*)gp, g1 = *(const float4*)(gp + 4);
    float4 b0 = *(const float4*)bp, b1 = *(const float4*)(bp + 4);
    float x[8];
    x[0] = (a.x - mu) * rs * g0.x + b0.x;  x[1] = (a.y - mu) * rs * g0.y + b0.y;
    x[2] = (a.z - mu) * rs * g0.z + b0.z;  x[3] = (a.w - mu) * rs * g0.w + b0.w;
    x[4] = (b.x - mu) * rs * g1.x + b1.x;  x[5] = (b.y - mu) * rs * g1.y + b1.y;
    x[6] = (b.z - mu) * rs * g1.z + b1.z;  x[7] = (b.w - mu) * rs * g1.w + b1.w;
    mk_pack(x, fh, fl);
}

// ---------------- weight prepass: fp32 [k][n] -> bf16 [n][k] (no Wq needed) ----------------
__global__ __launch_bounds__(256) void prep_kernel(
    const float* __restrict__ eW1, const float* __restrict__ eW2, const float* __restrict__ skipW,
    const float* __restrict__ Wk, const float* __restrict__ Wv,
    const float* __restrict__ Wih, const float* __restrict__ Whh,
    const float* __restrict__ mW1, const float* __restrict__ mW2, const float* __restrict__ Wt,
    u16* __restrict__ ws)
{
    int id = blockIdx.y;
    const float* src; int dstoff, logk, N;
    switch (id) {
        case 0:  src = eW1;   dstoff = OFF_EW1T;  logk = 9; N = 256; break;
        case 1:  src = eW2;   dstoff = OFF_EW2T;  logk = 8; N = 128; break;
        case 2:  src = skipW; dstoff = OFF_SKIPT; logk = 9; N = 128; break;
        case 3:  src = Wk;    dstoff = OFF_WKVT;  logk = 7; N = 128; break;
        case 4:  src = Wv;    dstoff = OFF_WKVT + 16384; logk = 7; N = 128; break;
        case 5:  src = Wih;   dstoff = OFF_WIHT;  logk = 7; N = 384; break;
        case 6:  src = Whh;   dstoff = OFF_WHHT;  logk = 7; N = 384; break;
        case 7:  src = mW1;   dstoff = OFF_MW1T;  logk = 7; N = 128; break;
        case 8:  src = mW2;   dstoff = OFF_MW2T;  logk = 7; N = 128; break;
        default: src = Wt;    dstoff = OFF_WTT;   logk = 7; N = 128; break;
    }
    int idx = blockIdx.x * 256 + threadIdx.x;
    int K = 1 << logk;
    if (idx < K * N) {
        int n = idx >> logk, k = idx & (K - 1);
        ws[dstoff + idx] = f2b(src[k * N + n]);
    }
}

// ---------------- main fused kernel: 4 (b,t) rows per block ----------------
__global__ __launch_bounds__(256) void sa2_kernel(
    const float* __restrict__ obs,
    const float* __restrict__ eb1, const float* __restrict__ eb2,
    const float* __restrict__ slot_mu,
    const float* __restrict__ Wq,
    const float* __restrict__ bih, const float* __restrict__ bhh,
    const float* __restrict__ mb1, const float* __restrict__ mb2,
    const float* __restrict__ g_in, const float* __restrict__ be_in,
    const float* __restrict__ g_sl, const float* __restrict__ be_sl,
    const float* __restrict__ g_ml, const float* __restrict__ be_ml,
    const u16* __restrict__ ws, float* __restrict__ out)
{
    __shared__ __align__(16) float slots_s[64 * 132];      // 33792 B
    __shared__ __align__(16) float scratch[4352];          // enc: obs(4x516)+h(4x260)+z(4x132); iter: hid u16 4x16x136
    __shared__ __align__(16) float k_s[4 * 132];
    __shared__ __align__(16) float v_s[4 * 132];
    __shared__ __align__(16) float par_s[6 * 128];         // gin, bin, gsl, bsl, gml, bml
    __shared__ __align__(16) float bias_s[512];            // b_rz[256], bin_[128], bhn_[128]
    __shared__ __align__(16) float gv_s[4 * 392];          // per-row v@Wih (384) padded
    __shared__ __align__(16) float gkq_s[4 * 132];         // per-row g_sl * (Wq@k)
    __shared__ float sgkq_s[4], bkq_s[4];
    __shared__ float rs_s[64];
    __shared__ float zmu_s[4], zrs_s[4];

    float* obs_s = scratch;            // 4 x 516
    float* h_s   = scratch + 2064;     // 4 x 260
    float* z_s   = scratch + 3104;     // 4 x 132
    u16*   hid_s = (u16*)scratch;      // 4 groups x 16 x 136 (iter phase)

    const int tid = threadIdx.x;
    const int wave = tid >> 6, lane = tid & 63;
    const int l15 = lane & 15, quad = lane >> 4;
    const int r0 = blockIdx.x * 4;

    // ---- stage params / biases / obs ----
    if (tid < 128) {
        par_s[tid]       = g_in[tid];  par_s[128 + tid] = be_in[tid];
        par_s[256 + tid] = g_sl[tid];  par_s[384 + tid] = be_sl[tid];
        par_s[512 + tid] = g_ml[tid];  par_s[640 + tid] = be_ml[tid];
        bias_s[256 + tid] = bih[256 + tid];
        bias_s[384 + tid] = bhh[256 + tid];
    }
    if (tid < 256) bias_s[tid] = bih[tid] + bhh[tid];
    for (int i4 = tid; i4 < 512; i4 += 256) {
        int g2 = i4 >> 7, c4 = i4 & 127;
        *((float4*)(obs_s + g2 * 516) + c4) = *((const float4*)(obs + (size_t)(r0 + g2) * 512) + c4);
    }
    __syncthreads();

    // ---- encoder layer 1: h = gelu(obs@W1 + b1); M-tile has rows 0-3 valid ----
    {
        f32x4 acc[4] = {{0}, {0}, {0}, {0}};
        const float* abase = obs_s + (l15 & 3) * 516;
#pragma unroll 1
        for (int ks = 0; ks < 16; ++ks) {
            FragU ah, al;
            mk_raw(abase + ks * 32 + quad * 8, ah, al);
#pragma unroll
            for (int tt = 0; tt < 4; ++tt) {
                int row = (wave * 4 + tt) * 16 + l15;
                FragU b; b.u = *(const uint4*)(ws + OFF_EW1T + row * 512 + ks * 32 + quad * 8);
                MFMA2(acc[tt], ah.v, al.v, b.v);
            }
        }
        {
            f32x4 av = acc[0];
            if (quad == 1) av = acc[1];
            if (quad == 2) av = acc[2];
            if (quad == 3) av = acc[3];
            int col = (wave * 4 + quad) * 16 + l15;
            float bb = eb1[col];
#pragma unroll
            for (int reg = 0; reg < 4; ++reg) {
                float x = av[reg] + bb;
                h_s[reg * 260 + col] = 0.5f * x * (1.0f + erff(x * 0.7071067811865475f));
            }
        }
    }
    __syncthreads();

    // ---- z = tanh(h@W2 + b2 + obs@skip) ----
    {
        f32x4 acc[2] = {{0}, {0}};
        const float* hbase = h_s + (l15 & 3) * 260;
#pragma unroll 1
        for (int ks = 0; ks < 8; ++ks) {
            FragU ah, al;
            mk_raw(hbase + ks * 32 + quad * 8, ah, al);
#pragma unroll
            for (int tt = 0; tt < 2; ++tt) {
                int row = (wave * 2 + tt) * 16 + l15;
                FragU b; b.u = *(const uint4*)(ws + OFF_EW2T + row * 256 + ks * 32 + quad * 8);
                MFMA2(acc[tt], ah.v, al.v, b.v);
            }
        }
        const float* obase = obs_s + (l15 & 3) * 516;
#pragma unroll 1
        for (int ks = 0; ks < 16; ++ks) {
            FragU ah, al;
            mk_raw(obase + ks * 32 + quad * 8, ah, al);
#pragma unroll
            for (int tt = 0; tt < 2; ++tt) {
                int row = (wave * 2 + tt) * 16 + l15;
                FragU b; b.u = *(const uint4*)(ws + OFF_SKIPT + row * 512 + ks * 32 + quad * 8);
                MFMA2(acc[tt], ah.v, al.v, b.v);
            }
        }
        if (quad < 2) {
            f32x4 av = (quad == 0) ? acc[0] : acc[1];
            int col = (wave * 2 + quad) * 16 + l15;
            float bb = eb2[col];
#pragma unroll
            for (int reg = 0; reg < 4; ++reg)
                z_s[reg * 132 + col] = tanhf(av[reg] + bb);
        }
    }
    __syncthreads();

    // ---- LN(z) stats: wave w computes row w stats ----
    {
        const float* row = z_s + wave * 132;
        float x0 = row[lane], x1 = row[64 + lane];
        float s = x0 + x1;
        s += __shfl_xor(s, 1);  s += __shfl_xor(s, 2);  s += __shfl_xor(s, 4);
        s += __shfl_xor(s, 8);  s += __shfl_xor(s, 16); s += __shfl_xor(s, 32);
        float mu = s * (1.0f / 128.0f);
        float d0 = x0 - mu, d1 = x1 - mu;
        float v = fmaf(d0, d0, d1 * d1);
        v += __shfl_xor(v, 1);  v += __shfl_xor(v, 2);  v += __shfl_xor(v, 4);
        v += __shfl_xor(v, 8);  v += __shfl_xor(v, 16); v += __shfl_xor(v, 32);
        if (lane == 0) { zmu_s[wave] = mu; zrs_s[wave] = rsqrtf(v * (1.0f / 128.0f) + 1e-5f); }
    }
    __syncthreads();

    // ---- k,v = LN(z) @ [Wk|Wv] ----
    {
        f32x4 acc[4] = {{0}, {0}, {0}, {0}};
        const float* zbase = z_s + (l15 & 3) * 132;
        float zmu = zmu_s[l15 & 3], zrs = zrs_s[l15 & 3];
#pragma unroll 1
        for (int ks = 0; ks < 4; ++ks) {
            FragU ah, al;
            mk_aff(zbase + ks * 32 + quad * 8, zmu, zrs,
                   par_s + ks * 32 + quad * 8, par_s + 128 + ks * 32 + quad * 8, ah, al);
#pragma unroll
            for (int tt = 0; tt < 4; ++tt) {
                int row = (wave * 4 + tt) * 16 + l15;
                FragU b; b.u = *(const uint4*)(ws + OFF_WKVT + row * 128 + ks * 32 + quad * 8);
                MFMA2(acc[tt], ah.v, al.v, b.v);
            }
        }
        {
            f32x4 av = acc[0];
            if (quad == 1) av = acc[1];
            if (quad == 2) av = acc[2];
            if (quad == 3) av = acc[3];
            int col = (wave * 4 + quad) * 16 + l15;
#pragma unroll
            for (int reg = 0; reg < 4; ++reg) {
                if (col < 128) k_s[reg * 132 + col] = av[reg];
                else           v_s[reg * 132 + col - 128] = av[reg];
            }
        }
    }
    __syncthreads();

    // ---- KQ precompute (plain VALU, fp32): kq[r][j] = sum_e k_r[e] * Wq[j*128+e] ----
    for (int t5 = tid; t5 < 512; t5 += 256) {
        int r = t5 >> 7, j = t5 & 127;
        const float* krow = k_s + r * 132;
        const float* wrow = Wq + j * 128;
        float a0 = 0, a1 = 0, a2 = 0, a3 = 0;
        for (int e = 0; e < 128; e += 4) {
            float4 wv = *(const float4*)(wrow + e);
            float4 kv = *(const float4*)(krow + e);
            a0 = fmaf(wv.x, kv.x, a0); a1 = fmaf(wv.y, kv.y, a1);
            a2 = fmaf(wv.z, kv.z, a2); a3 = fmaf(wv.w, kv.w, a3);
        }
        gkq_s[r * 132 + j] = (a0 + a1) + (a2 + a3);
    }

    // ---- GV precompute: gv[r][j] = sum_d v[r][d] * Wih[d][j]  (j in [0,384)) ----
    {
        f32x4 ag[6] = {{0}, {0}, {0}, {0}, {0}, {0}};
        const float* vbase = v_s + (l15 & 3) * 132;
#pragma unroll 1
        for (int ks = 0; ks < 4; ++ks) {
            FragU ah, al;
            mk_raw(vbase + ks * 32 + quad * 8, ah, al);
#pragma unroll
            for (int tt = 0; tt < 6; ++tt) {
                int row = (wave * 6 + tt) * 16 + l15;
                FragU b; b.u = *(const uint4*)(ws + OFF_WIHT + row * 128 + ks * 32 + quad * 8);
                MFMA2(ag[tt], ah.v, al.v, b.v);
            }
        }
#pragma unroll
        for (int tt = 0; tt < 6; ++tt) {
            if ((tt & 3) == quad) {
                int col = (wave * 6 + tt) * 16 + l15;
#pragma unroll
                for (int reg = 0; reg < 4; ++reg)
                    gv_s[reg * 392 + col] = ag[tt][reg];
            }
        }
    }
    __syncthreads();   // gkq_s/gv_s complete (gkq rows written by waves 0-1 only)

    // ---- finalize gkq: gkq = g_sl*kq; sgkq = sum(gkq); bkq = sum(be_sl*kq) ----
    // wave w owns row w (wave-local thereafter)
    {
        float* kqrow = gkq_s + wave * 132;
        float k0 = kqrow[lane], k1 = kqrow[64 + lane];
        float gk0 = par_s[256 + lane] * k0, gk1 = par_s[256 + 64 + lane] * k1;
        float bk = par_s[384 + lane] * k0 + par_s[384 + 64 + lane] * k1;
        float s = gk0 + gk1;
        s += __shfl_xor(s, 1);  s += __shfl_xor(s, 2);  s += __shfl_xor(s, 4);
        s += __shfl_xor(s, 8);  s += __shfl_xor(s, 16); s += __shfl_xor(s, 32);
        bk += __shfl_xor(bk, 1);  bk += __shfl_xor(bk, 2);  bk += __shfl_xor(bk, 4);
        bk += __shfl_xor(bk, 8);  bk += __shfl_xor(bk, 16); bk += __shfl_xor(bk, 32);
        kqrow[lane] = gk0; kqrow[64 + lane] = gk1;
        if (lane == 0) { sgkq_s[wave] = s; bkq_s[wave] = bk; }
    }
    __syncthreads();

    // ---- slot loop: wave w owns group g=w ----
    const int g = wave;
    const int srow0 = g * 16;
    for (int i4 = lane; i4 < 512; i4 += 64) {
        int row = i4 >> 5, c4 = i4 & 31;
        *((float4*)(slots_s + (srow0 + row) * 132) + c4) = *((const float4*)slot_mu + i4);
    }
    const float sgkq = sgkq_s[g], bkq = bkq_s[g];
    const float* gkrow = gkq_s + g * 132;
    const float* gvrow = gv_s + g * 392;

    for (int iter = 0; iter < 3; ++iter) {
        // ---- fused LN-stats + logit dot + softmax (no MFMA, no separate LN pass) ----
        float attn_me;
        {
            const float* rowp = slots_s + (srow0 + l15) * 132;
            float s0 = 0, s1 = 0, s2 = 0, s3 = 0;
            float q0 = 0, q1 = 0, q2 = 0, q3 = 0;
            float d0 = 0, d1 = 0, d2 = 0, d3 = 0;
#pragma unroll
            for (int j = 0; j < 8; ++j) {
                float x0 = rowp[quad + 16 * j],      gg0 = gkrow[quad + 16 * j];
                float x1 = rowp[quad + 16 * j + 4],  gg1 = gkrow[quad + 16 * j + 4];
                float x2 = rowp[quad + 16 * j + 8],  gg2 = gkrow[quad + 16 * j + 8];
                float x3 = rowp[quad + 16 * j + 12], gg3 = gkrow[quad + 16 * j + 12];
                s0 += x0; s1 += x1; s2 += x2; s3 += x3;
                q0 = fmaf(x0, x0, q0); q1 = fmaf(x1, x1, q1);
                q2 = fmaf(x2, x2, q2); q3 = fmaf(x3, x3, q3);
                d0 = fmaf(x0, gg0, d0); d1 = fmaf(x1, gg1, d1);
                d2 = fmaf(x2, gg2, d2); d3 = fmaf(x3, gg3, d3);
            }
            float s  = (s0 + s1) + (s2 + s3);
            float qq = (q0 + q1) + (q2 + q3);
            float dd = (d0 + d1) + (d2 + d3);
            s  += __shfl_xor(s, 16);  s  += __shfl_xor(s, 32);
            qq += __shfl_xor(qq, 16); qq += __shfl_xor(qq, 32);
            dd += __shfl_xor(dd, 16); dd += __shfl_xor(dd, 32);
            float mu = s * (1.0f / 128.0f);
            float var = qq * (1.0f / 128.0f) - mu * mu;
            float rs = rsqrtf(fmaxf(var, 0.0f) + 1e-5f);
            float logit = (rs * (dd - mu * sgkq) + bkq) * 0.08838834764831845f;
            float mx = fmaxf(logit, __shfl_xor(logit, 1));
            mx = fmaxf(mx, __shfl_xor(mx, 2));
            mx = fmaxf(mx, __shfl_xor(mx, 4));
            mx = fmaxf(mx, __shfl_xor(mx, 8));
            float e = expf(logit - mx);
            float den = e;
            den += __shfl_xor(den, 1);
            den += __shfl_xor(den, 2);
            den += __shfl_xor(den, 4);
            den += __shfl_xor(den, 8);
            attn_me = e / den;
        }

        // ---- GRU: gh = slots@Whh via MFMA; gi = attn * gv (folded, scalar) ----
        {
            float attn_r[4];
#pragma unroll
            for (int reg = 0; reg < 4; ++reg) attn_r[reg] = __shfl(attn_me, quad * 4 + reg);
            FragU ash[4], asl[4];
#pragma unroll
            for (int ks = 0; ks < 4; ++ks)
                mk_raw(slots_s + (srow0 + l15) * 132 + ks * 32 + quad * 8, ash[ks], asl[ks]);
#pragma unroll 1
            for (int cg = 0; cg < 8; ++cg) {
                f32x4 ar = {0}, az = {0}, anh = {0};
                const int rowb = cg * 16 + l15;
#pragma unroll
                for (int ks = 0; ks < 4; ++ks) {
                    const int koff = ks * 32 + quad * 8;
                    FragU b;
                    b.u = *(const uint4*)(ws + OFF_WHHT + rowb * 128 + koff);
                    MFMA2(ar, ash[ks].v, asl[ks].v, b.v);
                    b.u = *(const uint4*)(ws + OFF_WHHT + (128 + rowb) * 128 + koff);
                    MFMA2(az, ash[ks].v, asl[ks].v, b.v);
                    b.u = *(const uint4*)(ws + OFF_WHHT + (256 + rowb) * 128 + koff);
                    MFMA2(anh, ash[ks].v, asl[ks].v, b.v);
                }
                const int cc = cg * 16 + l15;
                float gvr = gvrow[cc], gvz = gvrow[128 + cc], gvn = gvrow[256 + cc];
#pragma unroll
                for (int reg = 0; reg < 4; ++reg) {
                    int row = srow0 + quad * 4 + reg;
                    float a = attn_r[reg];
                    float rg = sigmoidf_(fmaf(a, gvr, ar[reg] + bias_s[cc]));
                    float zg = sigmoidf_(fmaf(a, gvz, az[reg] + bias_s[128 + cc]));
                    float ng = tanhf(fmaf(a, gvn, bias_s[256 + cc]) + rg * (anh[reg] + bias_s[384 + cc]));
                    float hp = slots_s[row * 132 + cc];
                    slots_s[row * 132 + cc] = (1.0f - zg) * ng + zg * hp;
                }
            }
        }

        // ---- MLP: slots += relu(LN(slots)@W1+b1)@W2+b2 ----
        {
            const float* rowp = slots_s + (srow0 + l15) * 132;
            float s0 = 0, s1 = 0, s2 = 0, s3 = 0;
#pragma unroll
            for (int j = 0; j < 8; ++j) {
                s0 += rowp[quad + 16 * j];
                s1 += rowp[quad + 16 * j + 4];
                s2 += rowp[quad + 16 * j + 8];
                s3 += rowp[quad + 16 * j + 12];
            }
            float s = (s0 + s1) + (s2 + s3);
            s += __shfl_xor(s, 16); s += __shfl_xor(s, 32);
            float mu2 = s * (1.0f / 128.0f);
            float v0 = 0, v1 = 0, v2 = 0, v3 = 0;
#pragma unroll
            for (int j = 0; j < 8; ++j) {
                float d0 = rowp[quad + 16 * j] - mu2;      v0 = fmaf(d0, d0, v0);
                float d1 = rowp[quad + 16 * j + 4] - mu2;  v1 = fmaf(d1, d1, v1);
                float d2 = rowp[quad + 16 * j + 8] - mu2;  v2 = fmaf(d2, d2, v2);
                float d3 = rowp[quad + 16 * j + 12] - mu2; v3 = fmaf(d3, d3, v3);
            }
            float v = (v0 + v1) + (v2 + v3);
            v += __shfl_xor(v, 16); v += __shfl_xor(v, 32);
            float rs2 = rsqrtf(v * (1.0f / 128.0f) + 1e-5f);

            FragU ah[4], al[4];
#pragma unroll
            for (int ks = 0; ks < 4; ++ks)
                mk_aff(rowp + ks * 32 + quad * 8, mu2, rs2,
                       par_s + 512 + ks * 32 + quad * 8, par_s + 640 + ks * 32 + quad * 8,
                       ah[ks], al[ks]);
#pragma unroll 1
            for (int t = 0; t < 8; ++t) {
                f32x4 a = {0};
#pragma unroll
                for (int ks = 0; ks < 4; ++ks) {
                    FragU b; b.u = *(const uint4*)(ws + OFF_MW1T + (t * 16 + l15) * 128 + ks * 32 + quad * 8);
                    MFMA2(a, ah[ks].v, al[ks].v, b.v);
                }
                int cc = t * 16 + l15;
                float bb = mb1[cc];
#pragma unroll
                for (int reg = 0; reg < 4; ++reg)
                    hid_s[(srow0 + quad * 4 + reg) * 136 + cc] = f2b(fmaxf(a[reg] + bb, 0.0f));
            }
        }
        {
            FragU hf[4];
#pragma unroll
            for (int ks = 0; ks < 4; ++ks)
                hf[ks].u = *(const uint4*)(hid_s + (srow0 + l15) * 136 + ks * 32 + quad * 8);
#pragma unroll 1
            for (int t = 0; t < 8; ++t) {
                f32x4 a = {0};
#pragma unroll
                for (int ks = 0; ks < 4; ++ks) {
                    FragU b; b.u = *(const uint4*)(ws + OFF_MW2T + (t * 16 + l15) * 128 + ks * 32 + quad * 8);
                    MFMA(a, hf[ks].v, b.v);
                }
                int cc = t * 16 + l15;
                float bb = mb2[cc];
#pragma unroll
                for (int reg = 0; reg < 4; ++reg)
                    slots_s[(srow0 + quad * 4 + reg) * 132 + cc] += a[reg] + bb;
            }
        }
    }

    // ---- F.normalize + store (wave-local) ----
    {
        const float* rowp = slots_s + (srow0 + l15) * 132;
        float a0 = 0, a1 = 0, a2 = 0, a3 = 0;
#pragma unroll
        for (int j = 0; j < 8; ++j) {
            float x0 = rowp[quad + 16 * j];      a0 = fmaf(x0, x0, a0);
            float x1 = rowp[quad + 16 * j + 4];  a1 = fmaf(x1, x1, a1);
            float x2 = rowp[quad + 16 * j + 8];  a2 = fmaf(x2, x2, a2);
            float x3 = rowp[quad + 16 * j + 12]; a3 = fmaf(x3, x3, a3);
        }
        float ss = (a0 + a1) + (a2 + a3);
        ss += __shfl_xor(ss, 16); ss += __shfl_xor(ss, 32);
        if (quad == 0) rs_s[srow0 + l15] = 1.0f / fmaxf(sqrtf(ss), 1e-8f);
    }
    {
        size_t base = (size_t)(r0 + g) * 2048;
        for (int i4 = lane; i4 < 512; i4 += 64) {
            int row = i4 >> 5, c4 = i4 & 31;
            float4 vv = *((const float4*)(slots_s + (srow0 + row) * 132) + c4);
            float r = rs_s[srow0 + row];
            vv.x *= r; vv.y *= r; vv.z *= r; vv.w *= r;
            *((float4*)(out + base) + i4) = vv;
        }
    }
}

// ---------------- temporal chain: one block (one wave) per batch row, 63 steps ----------------
__global__ __launch_bounds__(64) void temporal2_kernel(
    const u16* __restrict__ ws, float* __restrict__ out)
{
    __shared__ __align__(16) u16 wt_s[128 * 136];
    __shared__ __align__(16) u16 prev_s[16 * 136];
    __shared__ __align__(16) float sa_s[16 * 132];

    const int lane = threadIdx.x;
    const int l15 = lane & 15, quad = lane >> 4;
    const int b = blockIdx.x;

    for (int idx = lane; idx < 2048; idx += 64) {
        int row = idx >> 4, ch = idx & 15;
        *(uint4*)(wt_s + row * 136 + ch * 8) = *(const uint4*)(ws + OFF_WTT + row * 128 + ch * 8);
    }
    {
        size_t base0 = (size_t)b * 64 * 2048;
        for (int i4 = lane; i4 < 512; i4 += 64) {
            float4 vv = *((const float4*)(out + base0) + i4);
            int row = i4 >> 5, c0 = (i4 & 31) * 4;
            ushort4 pk;
            pk.x = f2b(vv.x); pk.y = f2b(vv.y); pk.z = f2b(vv.z); pk.w = f2b(vv.w);
            *(ushort4*)(prev_s + row * 136 + c0) = pk;
        }
    }

    for (int t = 1; t < 64; ++t) {
        size_t base = ((size_t)b * 64 + t) * 2048;
        __syncthreads();
        FragU ap[4];
#pragma unroll
        for (int ks = 0; ks < 4; ++ks)
            ap[ks].u = *(const uint4*)(prev_s + l15 * 136 + ks * 32 + quad * 8);
        for (int i4 = lane; i4 < 512; i4 += 64) {
            float4 vv = *((const float4*)(out + base) + i4);
            *((float4*)(sa_s + (i4 >> 5) * 132) + (i4 & 31)) = vv;
        }
        f32x4 acc[8] = {{0}, {0}, {0}, {0}, {0}, {0}, {0}, {0}};
#pragma unroll
        for (int tt = 0; tt < 8; ++tt) {
#pragma unroll
            for (int ks = 0; ks < 4; ++ks) {
                FragU bv; bv.u = *(const uint4*)(wt_s + (tt * 16 + l15) * 136 + ks * 32 + quad * 8);
                MFMA(acc[tt], ap[ks].v, bv.v);
            }
        }
        __syncthreads();
#pragma unroll
        for (int tt = 0; tt < 8; ++tt) {
            int col = tt * 16 + l15;
#pragma unroll
            for (int reg = 0; reg < 4; ++reg) {
                int row = quad * 4 + reg;
                float bl = 0.7f * sa_s[row * 132 + col] + 0.3f * tanhf(acc[tt][reg]);
                out[base + row * 128 + col] = bl;
                prev_s[row * 136 + col] = f2b(bl);
            }
        }
    }
}

extern "C" void kernel_launch(void* const* d_in, const int* in_sizes, int n_in,
                              void* d_out, int out_size, void* d_ws, size_t ws_size,
                              hipStream_t stream) {
    const float* obs   = (const float*)d_in[0];
    const float* eW1   = (const float*)d_in[1];
    const float* eb1   = (const float*)d_in[2];
    const float* eW2   = (const float*)d_in[3];
    const float* eb2   = (const float*)d_in[4];
    const float* skipW = (const float*)d_in[5];
    const float* smu   = (const float*)d_in[6];
    const float* Wk    = (const float*)d_in[7];
    const float* Wv    = (const float*)d_in[8];
    const float* Wq    = (const float*)d_in[9];
    const float* Wih   = (const float*)d_in[10];
    const float* Whh   = (const float*)d_in[11];
    const float* bih   = (const float*)d_in[12];
    const float* bhh   = (const float*)d_in[13];
    const float* mW1   = (const float*)d_in[14];
    const float* mb1   = (const float*)d_in[15];
    const float* mW2   = (const float*)d_in[16];
    const float* mb2   = (const float*)d_in[17];
    const float* g_in  = (const float*)d_in[18];
    const float* be_in = (const float*)d_in[19];
    const float* g_sl  = (const float*)d_in[20];
    const float* be_sl = (const float*)d_in[21];
    const float* g_ml  = (const float*)d_in[22];
    const float* be_ml = (const float*)d_in[23];
    const float* Wt    = (const float*)d_in[24];
    float* out = (float*)d_out;
    u16* ws = (u16*)d_ws;

    prep_kernel<<<dim3(512, 10), 256, 0, stream>>>(eW1, eW2, skipW, Wk, Wv,
                                                   Wih, Whh, mW1, mW2, Wt, ws);
    sa2_kernel<<<B_ * T_ / 4, 256, 0, stream>>>(obs, eb1, eb2, smu, Wq, bih, bhh, mb1, mb2,
                                                g_in, be_in, g_sl, be_sl, g_ml, be_ml,
                                                ws, out);
    temporal2_kernel<<<B_, 64, 0, stream>>>(ws, out);
}

// Round 8
// 1548.756 us; speedup vs baseline: 2.0572x; 1.0948x over previous
//
#include <hip/hip_runtime.h>
#include <math.h>

#define B_ 256
#define T_ 64
#define DOBS 512
#define D_ 128
#define N_ 16
#define H_ 256

typedef unsigned short u16;
typedef short bf16x8 __attribute__((ext_vector_type(8)));
typedef float f32x4 __attribute__((ext_vector_type(4)));

union FragU { bf16x8 v; uint4 u; };

#define MFMA(ACC, A, Bv) (ACC) = __builtin_amdgcn_mfma_f32_16x16x32_bf16((A), (Bv), (ACC), 0, 0, 0)
#define MFMA2(ACC, AH, AL, Bv) do { MFMA(ACC, AH, Bv); MFMA(ACC, AL, Bv); } while (0)

// ws layout (u16 elements), all matrices transposed to [n][k] bf16:
#define OFF_EW1T   0        // 256x512
#define OFF_EW2T   131072   // 128x256
#define OFF_SKIPT  163840   // 128x512
#define OFF_WKVT   229376   // 256x128 (rows 0-127 Wk, 128-255 Wv)
#define OFF_WIHT   278528   // 384x128
#define OFF_WHHT   327680   // 384x128
#define OFF_MW1T   376832   // 128x128
#define OFF_MW2T   393216   // 128x128
#define OFF_WTT    409600   // 128x128

__device__ __forceinline__ unsigned rne16(float f) {
    unsigned u = __float_as_uint(f);
    return (u + 0x7FFFu + ((u >> 16) & 1u)) >> 16;
}
__device__ __forceinline__ float fromhi(unsigned h) { return __uint_as_float(h << 16); }
__device__ __forceinline__ u16 f2b(float f) { return (u16)rne16(f); }

// fast transcendentals: v_exp_f32 + v_rcp_f32 based; NaN-proof by construction.
// tanh clamped to +-15 (tanh(15)==1.0f in fp32); sigmoid safe at extremes
// (exp overflow -> inf -> rcp -> 0; exp underflow -> 0 -> 1).
__device__ __forceinline__ float ftanh(float x) {
    x = fminf(fmaxf(x, -15.0f), 15.0f);
    float e = __expf(-2.0f * x);
    return __fdividef(1.0f - e, 1.0f + e);
}
__device__ __forceinline__ float fsigmoid(float x) {
    return __fdividef(1.0f, 1.0f + __expf(-x));
}

__device__ __forceinline__ void mk_pack(const float* x, FragU& fh, FragU& fl) {
    unsigned h[8], l[8];
#pragma unroll
    for (int j = 0; j < 8; ++j) {
        h[j] = rne16(x[j]);
        l[j] = rne16(x[j] - fromhi(h[j]));
    }
    fh.u = make_uint4(h[0] | (h[1] << 16), h[2] | (h[3] << 16), h[4] | (h[5] << 16), h[6] | (h[7] << 16));
    fl.u = make_uint4(l[0] | (l[1] << 16), l[2] | (l[3] << 16), l[4] | (l[5] << 16), l[6] | (l[7] << 16));
}

__device__ __forceinline__ void mk_raw(const float* p, FragU& fh, FragU& fl) {
    float4 a = *(const float4*)p, b = *(const float4*)(p + 4);
    float x[8] = {a.x, a.y, a.z, a.w, b.x, b.y, b.z, b.w};
    mk_pack(x, fh, fl);
}

__device__ __forceinline__ void mk_aff(const float* p, float mu, float rs,
                                       const float* gp, const float* bp,
                                       FragU& fh, FragU& fl) {
    float4 a = *(const float4*)p, b = *(const float4*)(p + 4);
    float4 g0 = *(const float4*)gp, g1 = *(const float4*)(gp + 4);
    float4 b0 = *(const float4*)bp, b1 = *(const float4*)(bp + 4);
    float x[8];
    x[0] = (a.x - mu) * rs * g0.x + b0.x;  x[1] = (a.y - mu) * rs * g0.y + b0.y;
    x[2] = (a.z - mu) * rs * g0.z + b0.z;  x[3] = (a.w - mu) * rs * g0.w + b0.w;
    x[4] = (b.x - mu) * rs * g1.x + b1.x;  x[5] = (b.y - mu) * rs * g1.y + b1.y;
    x[6] = (b.z - mu) * rs * g1.z + b1.z;  x[7] = (b.w - mu) * rs * g1.w + b1.w;
    mk_pack(x, fh, fl);
}

// ---------------- weight prepass: fp32 [k][n] -> bf16 [n][k] (no Wq needed) ----------------
__global__ __launch_bounds__(256) void prep_kernel(
    const float* __restrict__ eW1, const float* __restrict__ eW2, const float* __restrict__ skipW,
    const float* __restrict__ Wk, const float* __restrict__ Wv,
    const float* __restrict__ Wih, const float* __restrict__ Whh,
    const float* __restrict__ mW1, const float* __restrict__ mW2, const float* __restrict__ Wt,
    u16* __restrict__ ws)
{
    int id = blockIdx.y;
    const float* src; int dstoff, logk, N;
    switch (id) {
        case 0:  src = eW1;   dstoff = OFF_EW1T;  logk = 9; N = 256; break;
        case 1:  src = eW2;   dstoff = OFF_EW2T;  logk = 8; N = 128; break;
        case 2:  src = skipW; dstoff = OFF_SKIPT; logk = 9; N = 128; break;
        case 3:  src = Wk;    dstoff = OFF_WKVT;  logk = 7; N = 128; break;
        case 4:  src = Wv;    dstoff = OFF_WKVT + 16384; logk = 7; N = 128; break;
        case 5:  src = Wih;   dstoff = OFF_WIHT;  logk = 7; N = 384; break;
        case 6:  src = Whh;   dstoff = OFF_WHHT;  logk = 7; N = 384; break;
        case 7:  src = mW1;   dstoff = OFF_MW1T;  logk = 7; N = 128; break;
        case 8:  src = mW2;   dstoff = OFF_MW2T;  logk = 7; N = 128; break;
        default: src = Wt;    dstoff = OFF_WTT;   logk = 7; N = 128; break;
    }
    int idx = blockIdx.x * 256 + threadIdx.x;
    int K = 1 << logk;
    if (idx < K * N) {
        int n = idx >> logk, k = idx & (K - 1);
        ws[dstoff + idx] = f2b(src[k * N + n]);
    }
}

// ---------------- main fused kernel: 4 (b,t) rows per block ----------------
__global__ __launch_bounds__(256) void sa2_kernel(
    const float* __restrict__ obs,
    const float* __restrict__ eb1, const float* __restrict__ eb2,
    const float* __restrict__ slot_mu,
    const float* __restrict__ Wq,
    const float* __restrict__ bih, const float* __restrict__ bhh,
    const float* __restrict__ mb1, const float* __restrict__ mb2,
    const float* __restrict__ g_in, const float* __restrict__ be_in,
    const float* __restrict__ g_sl, const float* __restrict__ be_sl,
    const float* __restrict__ g_ml, const float* __restrict__ be_ml,
    const u16* __restrict__ ws, float* __restrict__ out)
{
    __shared__ __align__(16) float slots_s[64 * 132];      // 33792 B
    __shared__ __align__(16) float scratch[4352];          // enc: obs(4x516)+h(4x260)+z(4x132); iter: hid u16 4x16x136
    __shared__ __align__(16) float k_s[4 * 132];
    __shared__ __align__(16) float v_s[4 * 132];
    __shared__ __align__(16) float par_s[6 * 128];         // gin, bin, gsl, bsl, gml, bml
    __shared__ __align__(16) float bias_s[512];            // b_rz[256], bin_[128], bhn_[128]
    __shared__ __align__(16) float gv_s[4 * 392];          // per-row v@Wih (384) padded
    __shared__ __align__(16) float gkq_s[4 * 132];         // per-row g_sl * (Wq@k)
    __shared__ float sgkq_s[4], bkq_s[4];
    __shared__ float rs_s[64];
    __shared__ float zmu_s[4], zrs_s[4];

    float* obs_s = scratch;            // 4 x 516
    float* h_s   = scratch + 2064;     // 4 x 260
    float* z_s   = scratch + 3104;     // 4 x 132
    u16*   hid_s = (u16*)scratch;      // 4 groups x 16 x 136 (iter phase)

    const int tid = threadIdx.x;
    const int wave = tid >> 6, lane = tid & 63;
    const int l15 = lane & 15, quad = lane >> 4;
    const int r0 = blockIdx.x * 4;

    // ---- stage params / biases / obs ----
    if (tid < 128) {
        par_s[tid]       = g_in[tid];  par_s[128 + tid] = be_in[tid];
        par_s[256 + tid] = g_sl[tid];  par_s[384 + tid] = be_sl[tid];
        par_s[512 + tid] = g_ml[tid];  par_s[640 + tid] = be_ml[tid];
        bias_s[256 + tid] = bih[256 + tid];
        bias_s[384 + tid] = bhh[256 + tid];
    }
    if (tid < 256) bias_s[tid] = bih[tid] + bhh[tid];
    for (int i4 = tid; i4 < 512; i4 += 256) {
        int g2 = i4 >> 7, c4 = i4 & 127;
        *((float4*)(obs_s + g2 * 516) + c4) = *((const float4*)(obs + (size_t)(r0 + g2) * 512) + c4);
    }
    __syncthreads();

    // ---- encoder layer 1: h = gelu(obs@W1 + b1); M-tile has rows 0-3 valid ----
    {
        f32x4 acc[4] = {{0}, {0}, {0}, {0}};
        const float* abase = obs_s + (l15 & 3) * 516;
#pragma unroll 1
        for (int ks = 0; ks < 16; ++ks) {
            FragU ah, al;
            mk_raw(abase + ks * 32 + quad * 8, ah, al);
#pragma unroll
            for (int tt = 0; tt < 4; ++tt) {
                int row = (wave * 4 + tt) * 16 + l15;
                FragU b; b.u = *(const uint4*)(ws + OFF_EW1T + row * 512 + ks * 32 + quad * 8);
                MFMA2(acc[tt], ah.v, al.v, b.v);
            }
        }
        {
            f32x4 av = acc[0];
            if (quad == 1) av = acc[1];
            if (quad == 2) av = acc[2];
            if (quad == 3) av = acc[3];
            int col = (wave * 4 + quad) * 16 + l15;
            float bb = eb1[col];
#pragma unroll
            for (int reg = 0; reg < 4; ++reg) {
                float x = av[reg] + bb;
                h_s[reg * 260 + col] = 0.5f * x * (1.0f + erff(x * 0.7071067811865475f));
            }
        }
    }
    __syncthreads();

    // ---- z = tanh(h@W2 + b2 + obs@skip) ----
    {
        f32x4 acc[2] = {{0}, {0}};
        const float* hbase = h_s + (l15 & 3) * 260;
#pragma unroll 1
        for (int ks = 0; ks < 8; ++ks) {
            FragU ah, al;
            mk_raw(hbase + ks * 32 + quad * 8, ah, al);
#pragma unroll
            for (int tt = 0; tt < 2; ++tt) {
                int row = (wave * 2 + tt) * 16 + l15;
                FragU b; b.u = *(const uint4*)(ws + OFF_EW2T + row * 256 + ks * 32 + quad * 8);
                MFMA2(acc[tt], ah.v, al.v, b.v);
            }
        }
        const float* obase = obs_s + (l15 & 3) * 516;
#pragma unroll 1
        for (int ks = 0; ks < 16; ++ks) {
            FragU ah, al;
            mk_raw(obase + ks * 32 + quad * 8, ah, al);
#pragma unroll
            for (int tt = 0; tt < 2; ++tt) {
                int row = (wave * 2 + tt) * 16 + l15;
                FragU b; b.u = *(const uint4*)(ws + OFF_SKIPT + row * 512 + ks * 32 + quad * 8);
                MFMA2(acc[tt], ah.v, al.v, b.v);
            }
        }
        if (quad < 2) {
            f32x4 av = (quad == 0) ? acc[0] : acc[1];
            int col = (wave * 2 + quad) * 16 + l15;
            float bb = eb2[col];
#pragma unroll
            for (int reg = 0; reg < 4; ++reg)
                z_s[reg * 132 + col] = ftanh(av[reg] + bb);
        }
    }
    __syncthreads();

    // ---- LN(z) stats: wave w computes row w stats ----
    {
        const float* row = z_s + wave * 132;
        float x0 = row[lane], x1 = row[64 + lane];
        float s = x0 + x1;
        s += __shfl_xor(s, 1);  s += __shfl_xor(s, 2);  s += __shfl_xor(s, 4);
        s += __shfl_xor(s, 8);  s += __shfl_xor(s, 16); s += __shfl_xor(s, 32);
        float mu = s * (1.0f / 128.0f);
        float d0 = x0 - mu, d1 = x1 - mu;
        float v = fmaf(d0, d0, d1 * d1);
        v += __shfl_xor(v, 1);  v += __shfl_xor(v, 2);  v += __shfl_xor(v, 4);
        v += __shfl_xor(v, 8);  v += __shfl_xor(v, 16); v += __shfl_xor(v, 32);
        if (lane == 0) { zmu_s[wave] = mu; zrs_s[wave] = rsqrtf(v * (1.0f / 128.0f) + 1e-5f); }
    }
    __syncthreads();

    // ---- k,v = LN(z) @ [Wk|Wv] ----
    {
        f32x4 acc[4] = {{0}, {0}, {0}, {0}};
        const float* zbase = z_s + (l15 & 3) * 132;
        float zmu = zmu_s[l15 & 3], zrs = zrs_s[l15 & 3];
#pragma unroll 1
        for (int ks = 0; ks < 4; ++ks) {
            FragU ah, al;
            mk_aff(zbase + ks * 32 + quad * 8, zmu, zrs,
                   par_s + ks * 32 + quad * 8, par_s + 128 + ks * 32 + quad * 8, ah, al);
#pragma unroll
            for (int tt = 0; tt < 4; ++tt) {
                int row = (wave * 4 + tt) * 16 + l15;
                FragU b; b.u = *(const uint4*)(ws + OFF_WKVT + row * 128 + ks * 32 + quad * 8);
                MFMA2(acc[tt], ah.v, al.v, b.v);
            }
        }
        {
            f32x4 av = acc[0];
            if (quad == 1) av = acc[1];
            if (quad == 2) av = acc[2];
            if (quad == 3) av = acc[3];
            int col = (wave * 4 + quad) * 16 + l15;
#pragma unroll
            for (int reg = 0; reg < 4; ++reg) {
                if (col < 128) k_s[reg * 132 + col] = av[reg];
                else           v_s[reg * 132 + col - 128] = av[reg];
            }
        }
    }
    __syncthreads();

    // ---- KQ precompute (plain VALU, fp32): kq[r][j] = sum_e k_r[e] * Wq[j*128+e] ----
    for (int t5 = tid; t5 < 512; t5 += 256) {
        int r = t5 >> 7, j = t5 & 127;
        const float* krow = k_s + r * 132;
        const float* wrow = Wq + j * 128;
        float a0 = 0, a1 = 0, a2 = 0, a3 = 0;
        for (int e = 0; e < 128; e += 4) {
            float4 wv = *(const float4*)(wrow + e);
            float4 kv = *(const float4*)(krow + e);
            a0 = fmaf(wv.x, kv.x, a0); a1 = fmaf(wv.y, kv.y, a1);
            a2 = fmaf(wv.z, kv.z, a2); a3 = fmaf(wv.w, kv.w, a3);
        }
        gkq_s[r * 132 + j] = (a0 + a1) + (a2 + a3);
    }

    // ---- GV precompute: gv[r][j] = sum_d v[r][d] * Wih[d][j]  (j in [0,384)) ----
    {
        f32x4 ag[6] = {{0}, {0}, {0}, {0}, {0}, {0}};
        const float* vbase = v_s + (l15 & 3) * 132;
#pragma unroll 1
        for (int ks = 0; ks < 4; ++ks) {
            FragU ah, al;
            mk_raw(vbase + ks * 32 + quad * 8, ah, al);
#pragma unroll
            for (int tt = 0; tt < 6; ++tt) {
                int row = (wave * 6 + tt) * 16 + l15;
                FragU b; b.u = *(const uint4*)(ws + OFF_WIHT + row * 128 + ks * 32 + quad * 8);
                MFMA2(ag[tt], ah.v, al.v, b.v);
            }
        }
#pragma unroll
        for (int tt = 0; tt < 6; ++tt) {
            if ((tt & 3) == quad) {
                int col = (wave * 6 + tt) * 16 + l15;
#pragma unroll
                for (int reg = 0; reg < 4; ++reg)
                    gv_s[reg * 392 + col] = ag[tt][reg];
            }
        }
    }
    __syncthreads();   // gkq_s/gv_s complete

    // ---- finalize gkq: gkq = g_sl*kq; sgkq = sum(gkq); bkq = sum(be_sl*kq) ----
    {
        float* kqrow = gkq_s + wave * 132;
        float k0 = kqrow[lane], k1 = kqrow[64 + lane];
        float gk0 = par_s[256 + lane] * k0, gk1 = par_s[256 + 64 + lane] * k1;
        float bk = par_s[384 + lane] * k0 + par_s[384 + 64 + lane] * k1;
        float s = gk0 + gk1;
        s += __shfl_xor(s, 1);  s += __shfl_xor(s, 2);  s += __shfl_xor(s, 4);
        s += __shfl_xor(s, 8);  s += __shfl_xor(s, 16); s += __shfl_xor(s, 32);
        bk += __shfl_xor(bk, 1);  bk += __shfl_xor(bk, 2);  bk += __shfl_xor(bk, 4);
        bk += __shfl_xor(bk, 8);  bk += __shfl_xor(bk, 16); bk += __shfl_xor(bk, 32);
        kqrow[lane] = gk0; kqrow[64 + lane] = gk1;
        if (lane == 0) { sgkq_s[wave] = s; bkq_s[wave] = bk; }
    }
    __syncthreads();

    // ---- slot loop: wave w owns group g=w ----
    const int g = wave;
    const int srow0 = g * 16;
    for (int i4 = lane; i4 < 512; i4 += 64) {
        int row = i4 >> 5, c4 = i4 & 31;
        *((float4*)(slots_s + (srow0 + row) * 132) + c4) = *((const float4*)slot_mu + i4);
    }
    const float sgkq = sgkq_s[g], bkq = bkq_s[g];
    const float* gkrow = gkq_s + g * 132;
    const float* gvrow = gv_s + g * 392;

    for (int iter = 0; iter < 3; ++iter) {
        // ---- fused LN-stats + logit dot + softmax (no MFMA) ----
        float attn_me;
        {
            const float* rowp = slots_s + (srow0 + l15) * 132;
            float s0 = 0, s1 = 0, s2 = 0, s3 = 0;
            float q0 = 0, q1 = 0, q2 = 0, q3 = 0;
            float d0 = 0, d1 = 0, d2 = 0, d3 = 0;
#pragma unroll
            for (int j = 0; j < 8; ++j) {
                float x0 = rowp[quad + 16 * j],      gg0 = gkrow[quad + 16 * j];
                float x1 = rowp[quad + 16 * j + 4],  gg1 = gkrow[quad + 16 * j + 4];
                float x2 = rowp[quad + 16 * j + 8],  gg2 = gkrow[quad + 16 * j + 8];
                float x3 = rowp[quad + 16 * j + 12], gg3 = gkrow[quad + 16 * j + 12];
                s0 += x0; s1 += x1; s2 += x2; s3 += x3;
                q0 = fmaf(x0, x0, q0); q1 = fmaf(x1, x1, q1);
                q2 = fmaf(x2, x2, q2); q3 = fmaf(x3, x3, q3);
                d0 = fmaf(x0, gg0, d0); d1 = fmaf(x1, gg1, d1);
                d2 = fmaf(x2, gg2, d2); d3 = fmaf(x3, gg3, d3);
            }
            float s  = (s0 + s1) + (s2 + s3);
            float qq = (q0 + q1) + (q2 + q3);
            float dd = (d0 + d1) + (d2 + d3);
            s  += __shfl_xor(s, 16);  s  += __shfl_xor(s, 32);
            qq += __shfl_xor(qq, 16); qq += __shfl_xor(qq, 32);
            dd += __shfl_xor(dd, 16); dd += __shfl_xor(dd, 32);
            float mu = s * (1.0f / 128.0f);
            float var = qq * (1.0f / 128.0f) - mu * mu;
            float rs = rsqrtf(fmaxf(var, 0.0f) + 1e-5f);
            float logit = (rs * (dd - mu * sgkq) + bkq) * 0.08838834764831845f;
            float mx = fmaxf(logit, __shfl_xor(logit, 1));
            mx = fmaxf(mx, __shfl_xor(mx, 2));
            mx = fmaxf(mx, __shfl_xor(mx, 4));
            mx = fmaxf(mx, __shfl_xor(mx, 8));
            float e = __expf(logit - mx);
            float den = e;
            den += __shfl_xor(den, 1);
            den += __shfl_xor(den, 2);
            den += __shfl_xor(den, 4);
            den += __shfl_xor(den, 8);
            attn_me = __fdividef(e, den);
        }

        // ---- GRU: gh = slots@Whh via MFMA; gi = attn * gv (folded, scalar) ----
        {
            float attn_r[4];
#pragma unroll
            for (int reg = 0; reg < 4; ++reg) attn_r[reg] = __shfl(attn_me, quad * 4 + reg);
            FragU ash[4], asl[4];
#pragma unroll
            for (int ks = 0; ks < 4; ++ks)
                mk_raw(slots_s + (srow0 + l15) * 132 + ks * 32 + quad * 8, ash[ks], asl[ks]);
#pragma unroll 1
            for (int cg = 0; cg < 8; ++cg) {
                f32x4 ar = {0}, az = {0}, anh = {0};
                const int rowb = cg * 16 + l15;
#pragma unroll
                for (int ks = 0; ks < 4; ++ks) {
                    const int koff = ks * 32 + quad * 8;
                    FragU b;
                    b.u = *(const uint4*)(ws + OFF_WHHT + rowb * 128 + koff);
                    MFMA2(ar, ash[ks].v, asl[ks].v, b.v);
                    b.u = *(const uint4*)(ws + OFF_WHHT + (128 + rowb) * 128 + koff);
                    MFMA2(az, ash[ks].v, asl[ks].v, b.v);
                    b.u = *(const uint4*)(ws + OFF_WHHT + (256 + rowb) * 128 + koff);
                    MFMA2(anh, ash[ks].v, asl[ks].v, b.v);
                }
                const int cc = cg * 16 + l15;
                float gvr = gvrow[cc], gvz = gvrow[128 + cc], gvn = gvrow[256 + cc];
#pragma unroll
                for (int reg = 0; reg < 4; ++reg) {
                    int row = srow0 + quad * 4 + reg;
                    float a = attn_r[reg];
                    float rg = fsigmoid(fmaf(a, gvr, ar[reg] + bias_s[cc]));
                    float zg = fsigmoid(fmaf(a, gvz, az[reg] + bias_s[128 + cc]));
                    float ng = ftanh(fmaf(a, gvn, bias_s[256 + cc]) + rg * (anh[reg] + bias_s[384 + cc]));
                    float hp = slots_s[row * 132 + cc];
                    slots_s[row * 132 + cc] = (1.0f - zg) * ng + zg * hp;
                }
            }
        }

        // ---- MLP: slots += relu(LN(slots)@W1+b1)@W2+b2 ----
        {
            const float* rowp = slots_s + (srow0 + l15) * 132;
            float s0 = 0, s1 = 0, s2 = 0, s3 = 0;
#pragma unroll
            for (int j = 0; j < 8; ++j) {
                s0 += rowp[quad + 16 * j];
                s1 += rowp[quad + 16 * j + 4];
                s2 += rowp[quad + 16 * j + 8];
                s3 += rowp[quad + 16 * j + 12];
            }
            float s = (s0 + s1) + (s2 + s3);
            s += __shfl_xor(s, 16); s += __shfl_xor(s, 32);
            float mu2 = s * (1.0f / 128.0f);
            float v0 = 0, v1 = 0, v2 = 0, v3 = 0;
#pragma unroll
            for (int j = 0; j < 8; ++j) {
                float d0 = rowp[quad + 16 * j] - mu2;      v0 = fmaf(d0, d0, v0);
                float d1 = rowp[quad + 16 * j + 4] - mu2;  v1 = fmaf(d1, d1, v1);
                float d2 = rowp[quad + 16 * j + 8] - mu2;  v2 = fmaf(d2, d2, v2);
                float d3 = rowp[quad + 16 * j + 12] - mu2; v3 = fmaf(d3, d3, v3);
            }
            float v = (v0 + v1) + (v2 + v3);
            v += __shfl_xor(v, 16); v += __shfl_xor(v, 32);
            float rs2 = rsqrtf(v * (1.0f / 128.0f) + 1e-5f);

            FragU ah[4], al[4];
#pragma unroll
            for (int ks = 0; ks < 4; ++ks)
                mk_aff(rowp + ks * 32 + quad * 8, mu2, rs2,
                       par_s + 512 + ks * 32 + quad * 8, par_s + 640 + ks * 32 + quad * 8,
                       ah[ks], al[ks]);
#pragma unroll 1
            for (int t = 0; t < 8; ++t) {
                f32x4 a = {0};
#pragma unroll
                for (int ks = 0; ks < 4; ++ks) {
                    FragU b; b.u = *(const uint4*)(ws + OFF_MW1T + (t * 16 + l15) * 128 + ks * 32 + quad * 8);
                    MFMA2(a, ah[ks].v, al[ks].v, b.v);
                }
                int cc = t * 16 + l15;
                float bb = mb1[cc];
#pragma unroll
                for (int reg = 0; reg < 4; ++reg)
                    hid_s[(srow0 + quad * 4 + reg) * 136 + cc] = f2b(fmaxf(a[reg] + bb, 0.0f));
            }
        }
        {
            FragU hf[4];
#pragma unroll
            for (int ks = 0; ks < 4; ++ks)
                hf[ks].u = *(const uint4*)(hid_s + (srow0 + l15) * 136 + ks * 32 + quad * 8);
#pragma unroll 1
            for (int t = 0; t < 8; ++t) {
                f32x4 a = {0};
#pragma unroll
                for (int ks = 0; ks < 4; ++ks) {
                    FragU b; b.u = *(const uint4*)(ws + OFF_MW2T + (t * 16 + l15) * 128 + ks * 32 + quad * 8);
                    MFMA(a, hf[ks].v, b.v);
                }
                int cc = t * 16 + l15;
                float bb = mb2[cc];
#pragma unroll
                for (int reg = 0; reg < 4; ++reg)
                    slots_s[(srow0 + quad * 4 + reg) * 132 + cc] += a[reg] + bb;
            }
        }
    }

    // ---- F.normalize + store (wave-local) ----
    {
        const float* rowp = slots_s + (srow0 + l15) * 132;
        float a0 = 0, a1 = 0, a2 = 0, a3 = 0;
#pragma unroll
        for (int j = 0; j < 8; ++j) {
            float x0 = rowp[quad + 16 * j];      a0 = fmaf(x0, x0, a0);
            float x1 = rowp[quad + 16 * j + 4];  a1 = fmaf(x1, x1, a1);
            float x2 = rowp[quad + 16 * j + 8];  a2 = fmaf(x2, x2, a2);
            float x3 = rowp[quad + 16 * j + 12]; a3 = fmaf(x3, x3, a3);
        }
        float ss = (a0 + a1) + (a2 + a3);
        ss += __shfl_xor(ss, 16); ss += __shfl_xor(ss, 32);
        if (quad == 0) rs_s[srow0 + l15] = 1.0f / fmaxf(sqrtf(ss), 1e-8f);
    }
    {
        size_t base = (size_t)(r0 + g) * 2048;
        for (int i4 = lane; i4 < 512; i4 += 64) {
            int row = i4 >> 5, c4 = i4 & 31;
            float4 vv = *((const float4*)(slots_s + (srow0 + row) * 132) + c4);
            float r = rs_s[srow0 + row];
            vv.x *= r; vv.y *= r; vv.z *= r; vv.w *= r;
            *((float4*)(out + base) + i4) = vv;
        }
    }
}

// ---------------- temporal chain: one block (one wave) per batch row, 63 steps ----------------
// sa[t] held in registers (blend layout), prefetched one step ahead; prev via LDS.
__global__ __launch_bounds__(64) void temporal2_kernel(
    const u16* __restrict__ ws, float* __restrict__ out)
{
    __shared__ __align__(16) u16 wt_s[128 * 136];
    __shared__ __align__(16) u16 prev_s[16 * 136];

    const int lane = threadIdx.x;
    const int l15 = lane & 15, quad = lane >> 4;
    const int b = blockIdx.x;

    for (int idx = lane; idx < 2048; idx += 64) {
        int row = idx >> 4, ch = idx & 15;
        *(uint4*)(wt_s + row * 136 + ch * 8) = *(const uint4*)(ws + OFF_WTT + row * 128 + ch * 8);
    }
    {
        size_t base0 = (size_t)b * 64 * 2048;
        for (int i4 = lane; i4 < 512; i4 += 64) {
            float4 vv = *((const float4*)(out + base0) + i4);
            int row = i4 >> 5, c0 = (i4 & 31) * 4;
            ushort4 pk;
            pk.x = f2b(vv.x); pk.y = f2b(vv.y); pk.z = f2b(vv.z); pk.w = f2b(vv.w);
            *(ushort4*)(prev_s + row * 136 + c0) = pk;
        }
    }
    // preload sa[1] into regs in blend layout: sa_cur[tt][reg] = out[b,1,quad*4+reg,tt*16+l15]
    float sa_cur[8][4];
    {
        size_t base1 = ((size_t)b * 64 + 1) * 2048;
#pragma unroll
        for (int tt = 0; tt < 8; ++tt)
#pragma unroll
            for (int reg = 0; reg < 4; ++reg)
                sa_cur[tt][reg] = out[base1 + (quad * 4 + reg) * 128 + tt * 16 + l15];
    }
    __syncthreads();

    for (int t = 1; t < 64; ++t) {
        size_t base = ((size_t)b * 64 + t) * 2048;
        // prefetch sa[t+1] (hides under MFMA + blend of this step)
        float sa_nxt[8][4];
        if (t < 63) {
            size_t nb = base + 2048;
#pragma unroll
            for (int tt = 0; tt < 8; ++tt)
#pragma unroll
                for (int reg = 0; reg < 4; ++reg)
                    sa_nxt[tt][reg] = out[nb + (quad * 4 + reg) * 128 + tt * 16 + l15];
        }
        FragU ap[4];
#pragma unroll
        for (int ks = 0; ks < 4; ++ks)
            ap[ks].u = *(const uint4*)(prev_s + l15 * 136 + ks * 32 + quad * 8);
        f32x4 acc[8] = {{0}, {0}, {0}, {0}, {0}, {0}, {0}, {0}};
#pragma unroll
        for (int tt = 0; tt < 8; ++tt) {
#pragma unroll
            for (int ks = 0; ks < 4; ++ks) {
                FragU bv; bv.u = *(const uint4*)(wt_s + (tt * 16 + l15) * 136 + ks * 32 + quad * 8);
                MFMA(acc[tt], ap[ks].v, bv.v);
            }
        }
#pragma unroll
        for (int tt = 0; tt < 8; ++tt) {
            int col = tt * 16 + l15;
#pragma unroll
            for (int reg = 0; reg < 4; ++reg) {
                int row = quad * 4 + reg;
                float bl = 0.7f * sa_cur[tt][reg] + 0.3f * ftanh(acc[tt][reg]);
                out[base + row * 128 + col] = bl;
                prev_s[row * 136 + col] = f2b(bl);
            }
        }
        __syncthreads();  // prev_s writes visible for next step's ap reads
        if (t < 63) {
#pragma unroll
            for (int tt = 0; tt < 8; ++tt)
#pragma unroll
                for (int reg = 0; reg < 4; ++reg)
                    sa_cur[tt][reg] = sa_nxt[tt][reg];
        }
    }
}

extern "C" void kernel_launch(void* const* d_in, const int* in_sizes, int n_in,
                              void* d_out, int out_size, void* d_ws, size_t ws_size,
                              hipStream_t stream) {
    const float* obs   = (const float*)d_in[0];
    const float* eW1   = (const float*)d_in[1];
    const float* eb1   = (const float*)d_in[2];
    const float* eW2   = (const float*)d_in[3];
    const float* eb2   = (const float*)d_in[4];
    const float* skipW = (const float*)d_in[5];
    const float* smu   = (const float*)d_in[6];
    const float* Wk    = (const float*)d_in[7];
    const float* Wv    = (const float*)d_in[8];
    const float* Wq    = (const float*)d_in[9];
    const float* Wih   = (const float*)d_in[10];
    const float* Whh   = (const float*)d_in[11];
    const float* bih   = (const float*)d_in[12];
    const float* bhh   = (const float*)d_in[13];
    const float* mW1   = (const float*)d_in[14];
    const float* mb1   = (const float*)d_in[15];
    const float* mW2   = (const float*)d_in[16];
    const float* mb2   = (const float*)d_in[17];
    const float* g_in  = (const float*)d_in[18];
    const float* be_in = (const float*)d_in[19];
    const float* g_sl  = (const float*)d_in[20];
    const float* be_sl = (const float*)d_in[21];
    const float* g_ml  = (const float*)d_in[22];
    const float* be_ml = (const float*)d_in[23];
    const float* Wt    = (const float*)d_in[24];
    float* out = (float*)d_out;
    u16* ws = (u16*)d_ws;

    prep_kernel<<<dim3(512, 10), 256, 0, stream>>>(eW1, eW2, skipW, Wk, Wv,
                                                   Wih, Whh, mW1, mW2, Wt, ws);
    sa2_kernel<<<B_ * T_ / 4, 256, 0, stream>>>(obs, eb1, eb2, smu, Wq, bih, bhh, mb1, mb2,
                                                g_in, be_in, g_sl, be_sl, g_ml, be_ml,
                                                ws, out);
    temporal2_kernel<<<B_, 64, 0, stream>>>(ws, out);
}